// Round 1
// baseline (2887.921 us; speedup 1.0000x reference)
//
#include <hip/hip_runtime.h>

typedef __attribute__((ext_vector_type(8))) short bf16x8;
typedef __attribute__((ext_vector_type(4))) float f32x4;

#define N_LAYER 4
#define QLEN 512
#define MLEN 512
#define KLEN 1024
#define BSZ 4
#define DM 1024
#define NH 16
#define DH 64
#define DINNER 4096

__device__ __forceinline__ unsigned short f2bf(float x) {
    unsigned u = __float_as_uint(x);
    u += 0x7fffu + ((u >> 16) & 1u);
    return (unsigned short)(u >> 16);
}
__device__ __forceinline__ float bf2f(unsigned short v) {
    return __uint_as_float(((unsigned)v) << 16);
}

// ---------------------------------------------------------------------------
// Weight transpose + f32->bf16:  W (K x N) -> WT (N x K) bf16
// ---------------------------------------------------------------------------
__global__ __launch_bounds__(256)
void transpose_w(const float* __restrict__ W, unsigned short* __restrict__ WT,
                 int K, int N) {
    __shared__ float tile[32][33];
    const int tx = threadIdx.x & 31, ty = threadIdx.x >> 5;
    const int bx = blockIdx.x, by = blockIdx.y;
#pragma unroll
    for (int i = 0; i < 4; ++i)
        tile[ty + i * 8][tx] = W[(size_t)(by * 32 + ty + i * 8) * N + bx * 32 + tx];
    __syncthreads();
#pragma unroll
    for (int i = 0; i < 4; ++i)
        WT[(size_t)(bx * 32 + ty + i * 8) * K + by * 32 + tx] = f2bf(tile[tx][ty + i * 8]);
}

// ---------------------------------------------------------------------------
// GEMM: C[M,N] = A[M,K] @ B[K,N], A bf16 row-major, BT = B^T bf16 (N x K)
// MODE 0: C f32.  MODE 1: Cbf = bf16(relu(acc + bias[col])).  MODE 2: C = acc + bias[col].
// 128x128 tile, BK=64, 4 waves of 64x64, 16x16x32 bf16 MFMA.
// ---------------------------------------------------------------------------
template <int MODE>
__global__ __launch_bounds__(256)
void gemm_bt(const unsigned short* __restrict__ A, const unsigned short* __restrict__ BT,
             float* __restrict__ C, unsigned short* __restrict__ Cbf,
             const float* __restrict__ bias, int M, int N, int K) {
    __shared__ unsigned short lA[128 * 64];
    __shared__ unsigned short lB[128 * 64];
    const int tid = threadIdx.x;
    const int w = tid >> 6, l = tid & 63;
    const int lane15 = l & 15, lh = l >> 4;
    const int bm = blockIdx.y, bn = blockIdx.x;
    const int wr = (w >> 1) * 64, wc = (w & 1) * 64;

    f32x4 acc[4][4] = {};

    const int srow = tid >> 3;         // 0..31
    const int scol = (tid & 7) * 8;    // 0..56

    for (int k0 = 0; k0 < K; k0 += 64) {
        uint4 va[4], vb[4];
#pragma unroll
        for (int it = 0; it < 4; ++it) {
            int r = it * 32 + srow;
            va[it] = *(const uint4*)(A + (size_t)(bm * 128 + r) * K + k0 + scol);
            vb[it] = *(const uint4*)(BT + (size_t)(bn * 128 + r) * K + k0 + scol);
        }
        __syncthreads();
#pragma unroll
        for (int it = 0; it < 4; ++it) {
            int r = it * 32 + srow;
            *(uint4*)(lA + r * 64 + scol) = va[it];
            *(uint4*)(lB + r * 64 + scol) = vb[it];
        }
        __syncthreads();
#pragma unroll
        for (int kk = 0; kk < 2; ++kk) {
            bf16x8 af[4], bfr[4];
#pragma unroll
            for (int f = 0; f < 4; ++f) {
                af[f]  = *(const bf16x8*)(lA + (wr + f * 16 + lane15) * 64 + kk * 32 + lh * 8);
                bfr[f] = *(const bf16x8*)(lB + (wc + f * 16 + lane15) * 64 + kk * 32 + lh * 8);
            }
#pragma unroll
            for (int mi = 0; mi < 4; ++mi)
#pragma unroll
                for (int ni = 0; ni < 4; ++ni)
                    acc[mi][ni] = __builtin_amdgcn_mfma_f32_16x16x32_bf16(
                        af[mi], bfr[ni], acc[mi][ni], 0, 0, 0);
        }
    }

#pragma unroll
    for (int mi = 0; mi < 4; ++mi) {
        int rowb = bm * 128 + wr + mi * 16 + lh * 4;
#pragma unroll
        for (int ni = 0; ni < 4; ++ni) {
            int col = bn * 128 + wc + ni * 16 + lane15;
#pragma unroll
            for (int r = 0; r < 4; ++r) {
                float x = acc[mi][ni][r];
                size_t o = (size_t)(rowb + r) * N + col;
                if (MODE == 0) {
                    C[o] = x;
                } else if (MODE == 1) {
                    x += bias[col];
                    Cbf[o] = f2bf(x > 0.f ? x : 0.f);
                } else {
                    C[o] = x + bias[col];
                }
            }
        }
    }
}

// ---------------------------------------------------------------------------
// Adaptive embedding: one block per token
// ---------------------------------------------------------------------------
__global__ __launch_bounds__(256)
void emb_kernel(const int* __restrict__ ids,
                const float* __restrict__ e0, const float* __restrict__ e1,
                const float* __restrict__ e2, const float* __restrict__ e3,
                const float* __restrict__ p0, const float* __restrict__ p1,
                const float* __restrict__ p2, const float* __restrict__ p3,
                float* __restrict__ h) {
    __shared__ float row[1024];
    const int t = blockIdx.x, tid = threadIdx.x;
    const int i = t >> 2, b = t & 3;
    const int id = ids[b * QLEN + i];
    const float* et; const float* pt; int di, lo;
    if (id < 20000)       { et = e0; pt = p0; di = 1024; lo = 0; }
    else if (id < 40000)  { et = e1; pt = p1; di = 256;  lo = 20000; }
    else if (id < 200000) { et = e2; pt = p2; di = 64;   lo = 40000; }
    else                  { et = e3; pt = p3; di = 16;   lo = 200000; }
    const int rix = id - lo;
    for (int k = tid; k < di; k += 256) row[k] = et[(size_t)rix * di + k];
    __syncthreads();
#pragma unroll
    for (int j = 0; j < 4; ++j) {
        int d = tid + j * 256;
        float s = 0.f;
#pragma unroll 8
        for (int k = 0; k < di; ++k) s = fmaf(row[k], pt[(size_t)k * DM + d], s);
        h[(size_t)t * DM + d] = s * 32.0f;
    }
}

// ---------------------------------------------------------------------------
// Positional embedding table (1024 x 1024), f32 + bf16
// ---------------------------------------------------------------------------
__global__ __launch_bounds__(256)
void pos_kernel(float* __restrict__ posf, unsigned short* __restrict__ posbf) {
    const int p = blockIdx.x, tid = threadIdx.x;
    const float ps = (float)(KLEN - 1 - p);
    const float c = -2.0f * 9.210340371976184f / 1024.0f; // -2*ln(10000)/D
#pragma unroll
    for (int j4 = 0; j4 < 4; ++j4) {
        int j = tid + j4 * 256;
        int m = (j < 512) ? j : j - 512;
        float freq = __expf((float)m * c);
        float ang = ps * freq;
        float v = (j < 512) ? sinf(ang) : cosf(ang);
        posf[(size_t)p * DM + j] = v;
        posbf[(size_t)p * DM + j] = f2bf(v);
    }
}

// ---------------------------------------------------------------------------
// cat = [mems_l ; h] -> bf16 (4096 x 1024)
// ---------------------------------------------------------------------------
__global__ __launch_bounds__(256)
void cat_kernel(const float* __restrict__ mem_l, const float* __restrict__ h,
                unsigned short* __restrict__ catbf) {
    const int t = blockIdx.x, tid = threadIdx.x;
    const float* src = (t < 2048) ? (mem_l + (size_t)t * DM) : (h + (size_t)(t - 2048) * DM);
    float4 v = ((const float4*)src)[tid];
    uint2 o;
    o.x = (unsigned)f2bf(v.x) | ((unsigned)f2bf(v.y) << 16);
    o.y = (unsigned)f2bf(v.z) | ((unsigned)f2bf(v.w) << 16);
    ((uint2*)(catbf + (size_t)t * DM))[tid] = o;
}

// ---------------------------------------------------------------------------
// Scatter w_heads (4096 x 3072 f32) -> Qw/Qr [b][n][i][d], K [b][n][j][d],
// VT [b][n][d][j]   (all bf16). Q gets +r_w_bias / +r_r_bias.
// ---------------------------------------------------------------------------
__global__ __launch_bounds__(256)
void scatter_qkv(const float* __restrict__ wh, const float* __restrict__ rwb,
                 const float* __restrict__ rrb, unsigned short* __restrict__ Qw,
                 unsigned short* __restrict__ Qr, unsigned short* __restrict__ Kb,
                 unsigned short* __restrict__ VTb) {
    const int t = blockIdx.x, tid = threadIdx.x;
    const int j = t >> 2, b = t & 3;
#pragma unroll
    for (int k = 0; k < 12; ++k) {
        int c = tid + k * 256;
        float val = wh[(size_t)t * 3072 + c];
        if (c < 1024) {
            if (j >= MLEN) {
                int i = j - MLEN;
                int n = c >> 6, d = c & 63;
                size_t o = ((size_t)(b * NH + n) * QLEN + i) * DH + d;
                Qw[o] = f2bf(val + rwb[c]);
                Qr[o] = f2bf(val + rrb[c]);
            }
        } else if (c < 2048) {
            int c2 = c - 1024;
            int n = c2 >> 6, d = c2 & 63;
            Kb[((size_t)(b * NH + n) * KLEN + j) * DH + d] = f2bf(val);
        } else {
            int c2 = c - 2048;
            int n = c2 >> 6, d = c2 & 63;
            VTb[((size_t)(b * NH + n) * DH + d) * KLEN + j] = f2bf(val);
        }
    }
}

// Scatter r_head_k (1024 x 1024 f32) -> Rb [n][j][d] bf16
__global__ __launch_bounds__(256)
void scatter_rk(const float* __restrict__ rk, unsigned short* __restrict__ Rb) {
    const int j = blockIdx.x, tid = threadIdx.x;
#pragma unroll
    for (int k = 0; k < 4; ++k) {
        int c = tid + k * 256;
        int n = c >> 6, d = c & 63;
        Rb[((size_t)n * KLEN + j) * DH + d] = f2bf(rk[(size_t)j * DM + c]);
    }
}

// ---------------------------------------------------------------------------
// Fused rel-attention, flash style. Block = (b, n, 64-row i-tile), 4 waves.
// score[i,j] = (Q_w·K[j] + BDraw[i, 511+j-i]) * 0.125, mask j > i+512.
// ---------------------------------------------------------------------------
__global__ __launch_bounds__(256)
void attn_kernel(const unsigned short* __restrict__ Qw, const unsigned short* __restrict__ Qr,
                 const unsigned short* __restrict__ Kb, const unsigned short* __restrict__ VTb,
                 const unsigned short* __restrict__ Rb, unsigned short* __restrict__ avec) {
    __shared__ unsigned short lK[64 * 64];
    __shared__ unsigned short lVT[64 * 64];
    __shared__ unsigned short lR[128 * 64];
    __shared__ unsigned short lBD[4][16 * 128];
    __shared__ unsigned short lP[4][16 * 64];

    const int tid = threadIdx.x;
    const int w = tid >> 6, l = tid & 63;
    const int lane15 = l & 15, lh = l >> 4;
    const int blk = blockIdx.x;
    const int it = blk & 7;
    const int bn = blk >> 3;          // b*16 + n
    const int n = bn & 15, b = bn >> 4;
    const int i0 = it * 64;
    const int rowl = w * 16 + lh * 4; // tile-local row base of this lane's 4 rows

    // Q fragments (resident in regs for all tiles)
    bf16x8 qw[2], qr[2];
    {
        size_t base = ((size_t)bn * QLEN + i0 + w * 16 + lane15) * DH + lh * 8;
        qw[0] = *(const bf16x8*)(Qw + base);
        qw[1] = *(const bf16x8*)(Qw + base + 32);
        qr[0] = *(const bf16x8*)(Qr + base);
        qr[1] = *(const bf16x8*)(Qr + base + 32);
    }

    f32x4 oacc[4] = {};
    float mrow[4], srow[4];
#pragma unroll
    for (int r = 0; r < 4; ++r) { mrow[r] = -1e30f; srow[r] = 0.f; }

    const int ntiles = it + 9;
    for (int jt = 0; jt < ntiles; ++jt) {
        const int j0 = jt * 64;
        const int rbase = 448 + (jt - it) * 64;
        __syncthreads();
        // stage K (64x64), VT (64x64), R band (128x64)
        {
            const uint4* sK = (const uint4*)(Kb + ((size_t)bn * KLEN + j0) * DH);
            ((uint4*)lK)[tid] = sK[tid];
            ((uint4*)lK)[tid + 256] = sK[tid + 256];
#pragma unroll
            for (int s = 0; s < 2; ++s) {
                int idx = s * 256 + tid;
                int d = idx >> 3, c = (idx & 7) * 8;
                *(uint4*)(lVT + d * 64 + c) =
                    *(const uint4*)(VTb + ((size_t)bn * DH + d) * KLEN + j0 + c);
            }
#pragma unroll
            for (int s = 0; s < 4; ++s) {
                int idx = s * 256 + tid;
                int rl = idx >> 3, c = (idx & 7) * 8;
                int rr = rbase + rl; if (rr > 1023) rr = 1023;
                *(uint4*)(lR + rl * 64 + c) =
                    *(const uint4*)(Rb + ((size_t)n * KLEN + rr) * DH + c);
            }
        }
        __syncthreads();

        // AC (4 n-frags) and BD (8 n-frags over the 128-wide r band)
        f32x4 sac[4] = {};
        f32x4 bd[8] = {};
#pragma unroll
        for (int kk = 0; kk < 2; ++kk) {
#pragma unroll
            for (int f = 0; f < 4; ++f) {
                bf16x8 kb = *(const bf16x8*)(lK + (f * 16 + lane15) * 64 + kk * 32 + lh * 8);
                sac[f] = __builtin_amdgcn_mfma_f32_16x16x32_bf16(qw[kk], kb, sac[f], 0, 0, 0);
            }
#pragma unroll
            for (int f = 0; f < 8; ++f) {
                bf16x8 rb = *(const bf16x8*)(lR + (f * 16 + lane15) * 64 + kk * 32 + lh * 8);
                bd[f] = __builtin_amdgcn_mfma_f32_16x16x32_bf16(qr[kk], rb, bd[f], 0, 0, 0);
            }
        }
        // park BD in LDS (per-wave region) for the diagonal-band gather
#pragma unroll
        for (int f = 0; f < 8; ++f)
#pragma unroll
            for (int r = 0; r < 4; ++r)
                lBD[w][(lh * 4 + r) * 128 + lane15 + 16 * f] = f2bf(bd[f][r]);

        float pv[4][4];
        float tmax[4] = {-1e30f, -1e30f, -1e30f, -1e30f};
        const bool lastTile = (jt == it + 8);
#pragma unroll
        for (int f = 0; f < 4; ++f) {
            int lj = lane15 + 16 * f;
#pragma unroll
            for (int r = 0; r < 4; ++r) {
                int li = rowl + r;
                float bdv = bf2f(lBD[w][(lh * 4 + r) * 128 + (63 + lj - li)]);
                float s = (sac[f][r] + bdv) * 0.125f;
                if (lastTile && (lj > li)) s = -1e30f;
                pv[f][r] = s;
                tmax[r] = fmaxf(tmax[r], s);
            }
        }
#pragma unroll
        for (int off = 1; off < 16; off <<= 1)
#pragma unroll
            for (int r = 0; r < 4; ++r)
                tmax[r] = fmaxf(tmax[r], __shfl_xor(tmax[r], off));

        float scal[4], tsum[4];
#pragma unroll
        for (int r = 0; r < 4; ++r) {
            float nm = fmaxf(mrow[r], tmax[r]);
            scal[r] = __expf(mrow[r] - nm);
            mrow[r] = nm;
            float ts = 0.f;
#pragma unroll
            for (int f = 0; f < 4; ++f) {
                float e = __expf(pv[f][r] - nm);
                pv[f][r] = e;
                ts += e;
            }
            tsum[r] = ts;
        }
#pragma unroll
        for (int off = 1; off < 16; off <<= 1)
#pragma unroll
            for (int r = 0; r < 4; ++r)
                tsum[r] += __shfl_xor(tsum[r], off);
#pragma unroll
        for (int r = 0; r < 4; ++r) {
            srow[r] = srow[r] * scal[r] + tsum[r];
#pragma unroll
            for (int f = 0; f < 4; ++f) oacc[f][r] *= scal[r];
        }
        // P -> bf16 LDS (per-wave), reload as A-fragments
#pragma unroll
        for (int f = 0; f < 4; ++f)
#pragma unroll
            for (int r = 0; r < 4; ++r)
                lP[w][(lh * 4 + r) * 64 + lane15 + 16 * f] = f2bf(pv[f][r]);
#pragma unroll
        for (int kk = 0; kk < 2; ++kk) {
            bf16x8 pa = *(const bf16x8*)(&lP[w][lane15 * 64 + kk * 32 + lh * 8]);
#pragma unroll
            for (int f = 0; f < 4; ++f) {
                bf16x8 vb = *(const bf16x8*)(lVT + (f * 16 + lane15) * 64 + kk * 32 + lh * 8);
                oacc[f] = __builtin_amdgcn_mfma_f32_16x16x32_bf16(pa, vb, oacc[f], 0, 0, 0);
            }
        }
    }

    // write attn_vec [t][n*64+d] bf16, t = i*4 + b
#pragma unroll
    for (int f = 0; f < 4; ++f)
#pragma unroll
        for (int r = 0; r < 4; ++r) {
            int i = i0 + rowl + r;
            int t = i * 4 + b;
            int col = n * 64 + lane15 + 16 * f;
            avec[(size_t)t * DM + col] = f2bf(oacc[f][r] / srow[r]);
        }
}

// ---------------------------------------------------------------------------
// LayerNorm: h = LN(hin + res) * g + b ; emits f32 h and bf16 h
// ---------------------------------------------------------------------------
__global__ __launch_bounds__(256)
void ln_kernel(const float* __restrict__ hin, const float* __restrict__ res,
               const float* __restrict__ g, const float* __restrict__ bb,
               float* __restrict__ hout, unsigned short* __restrict__ hbf) {
    __shared__ float ls[8];
    const int t = blockIdx.x, tid = threadIdx.x;
    float4 x = ((const float4*)(hin + (size_t)t * DM))[tid];
    float4 rr = ((const float4*)(res + (size_t)t * DM))[tid];
    float v0 = x.x + rr.x, v1 = x.y + rr.y, v2 = x.z + rr.z, v3 = x.w + rr.w;
    float s = v0 + v1 + v2 + v3;
    float sq = v0 * v0 + v1 * v1 + v2 * v2 + v3 * v3;
#pragma unroll
    for (int off = 1; off < 64; off <<= 1) {
        s += __shfl_xor(s, off);
        sq += __shfl_xor(sq, off);
    }
    const int w = tid >> 6;
    if ((tid & 63) == 0) { ls[w] = s; ls[4 + w] = sq; }
    __syncthreads();
    s = ls[0] + ls[1] + ls[2] + ls[3];
    sq = ls[4] + ls[5] + ls[6] + ls[7];
    float mu = s * (1.f / 1024.f);
    float var = sq * (1.f / 1024.f) - mu * mu;
    float rstd = rsqrtf(var + 1e-5f);
    float y[4] = {v0, v1, v2, v3};
    float4 of;
    uint2 ob;
    float* op = &of.x;
#pragma unroll
    for (int j = 0; j < 4; ++j) {
        int d = tid * 4 + j;
        op[j] = (y[j] - mu) * rstd * g[d] + bb[d];
    }
    ob.x = (unsigned)f2bf(of.x) | ((unsigned)f2bf(of.y) << 16);
    ob.y = (unsigned)f2bf(of.z) | ((unsigned)f2bf(of.w) << 16);
    ((float4*)(hout + (size_t)t * DM))[tid] = of;
    ((uint2*)(hbf + (size_t)t * DM))[tid] = ob;
}

// out[b][i][d] = h[i*4+b][d]
__global__ __launch_bounds__(256)
void out_kernel(const float* __restrict__ h, float* __restrict__ out) {
    const int t = blockIdx.x, tid = threadIdx.x;
    const int i = t >> 2, b = t & 3;
    ((float4*)(out + ((size_t)b * QLEN + i) * DM))[tid] =
        ((const float4*)(h + (size_t)t * DM))[tid];
}

// ---------------------------------------------------------------------------
extern "C" void kernel_launch(void* const* d_in, const int* in_sizes, int n_in,
                              void* d_out, int out_size, void* d_ws, size_t ws_size,
                              hipStream_t stream) {
    const int* ids = (const int*)d_in[0];
    const float* mems = (const float*)d_in[1];
    // emb/proj pointers resolved by element count (robust to dict order)
    const float* embp[4] = {nullptr, nullptr, nullptr, nullptr};
    const float* projp[4] = {nullptr, nullptr, nullptr, nullptr};
    const long long esz[4] = {20000LL * 1024, 20000LL * 256, 160000LL * 64, 67735LL * 16};
    const long long psz[4] = {1024LL * 1024, 256LL * 1024, 64LL * 1024, 16LL * 1024};
    for (int idx = 2; idx <= 9 && idx < n_in; ++idx) {
        long long s = in_sizes[idx];
        for (int c = 0; c < 4; ++c) {
            if (s == esz[c]) embp[c] = (const float*)d_in[idx];
            else if (s == psz[c]) projp[c] = (const float*)d_in[idx];
        }
    }
    const float* qkvW = (const float*)d_in[10];
    const float* rW   = (const float*)d_in[11];
    const float* oW   = (const float*)d_in[12];
    const float* rwb  = (const float*)d_in[13];
    const float* rrb  = (const float*)d_in[14];
    const float* ln1g = (const float*)d_in[15];
    const float* ln1b = (const float*)d_in[16];
    const float* ffw1 = (const float*)d_in[17];
    const float* ffb1 = (const float*)d_in[18];
    const float* ffw2 = (const float*)d_in[19];
    const float* ffb2 = (const float*)d_in[20];
    const float* ln2g = (const float*)d_in[21];
    const float* ln2b = (const float*)d_in[22];

    size_t off = 0;
    char* base = (char*)d_ws;
    auto alloc = [&](size_t bytes) -> char* {
        char* p = base + off;
        off = (off + bytes + 255) & ~(size_t)255;
        return p;
    };
    unsigned short* qkvT = (unsigned short*)alloc(3072ull * 1024 * 2);
    unsigned short* rT   = (unsigned short*)alloc(1024ull * 1024 * 2);
    unsigned short* oT   = (unsigned short*)alloc(1024ull * 1024 * 2);
    unsigned short* w1T  = (unsigned short*)alloc(4096ull * 1024 * 2);
    unsigned short* w2T  = (unsigned short*)alloc(1024ull * 4096 * 2);
    float* h             = (float*)alloc(2048ull * 1024 * 4);
    unsigned short* hbf  = (unsigned short*)alloc(2048ull * 1024 * 2);
    unsigned short* catb = (unsigned short*)alloc(4096ull * 1024 * 2);
    float* posf          = (float*)alloc(1024ull * 1024 * 4);
    unsigned short* posb = (unsigned short*)alloc(1024ull * 1024 * 2);
    float* wheads        = (float*)alloc(4096ull * 3072 * 4);
    float* rkf           = (float*)alloc(1024ull * 1024 * 4);
    unsigned short* Qw   = (unsigned short*)alloc(4ull * 16 * 512 * 64 * 2);
    unsigned short* Qr   = (unsigned short*)alloc(4ull * 16 * 512 * 64 * 2);
    unsigned short* Kb   = (unsigned short*)alloc(4ull * 16 * 1024 * 64 * 2);
    unsigned short* VTb  = (unsigned short*)alloc(4ull * 16 * 1024 * 64 * 2);
    unsigned short* Rb   = (unsigned short*)alloc(16ull * 1024 * 64 * 2);
    unsigned short* avec = (unsigned short*)alloc(2048ull * 1024 * 2);
    float* resid         = (float*)alloc(2048ull * 1024 * 4);
    unsigned short* ff1b = (unsigned short*)alloc(2048ull * 4096 * 2);
    (void)ws_size; (void)out_size;

    // ---- embeddings + positional table ----
    emb_kernel<<<2048, 256, 0, stream>>>(ids, embp[0], embp[1], embp[2], embp[3],
                                         projp[0], projp[1], projp[2], projp[3], h);
    pos_kernel<<<1024, 256, 0, stream>>>(posf, posb);

    for (int l = 0; l < N_LAYER; ++l) {
        const float* qkvWl = qkvW + (size_t)l * 1024 * 3072;
        const float* rWl   = rW + (size_t)l * 1024 * 1024;
        const float* oWl   = oW + (size_t)l * 1024 * 1024;
        const float* w1l   = ffw1 + (size_t)l * 1024 * 4096;
        const float* w2l   = ffw2 + (size_t)l * 4096 * 1024;

        transpose_w<<<dim3(3072 / 32, 1024 / 32), 256, 0, stream>>>(qkvWl, qkvT, 1024, 3072);
        transpose_w<<<dim3(1024 / 32, 1024 / 32), 256, 0, stream>>>(rWl, rT, 1024, 1024);
        transpose_w<<<dim3(1024 / 32, 1024 / 32), 256, 0, stream>>>(oWl, oT, 1024, 1024);
        transpose_w<<<dim3(4096 / 32, 1024 / 32), 256, 0, stream>>>(w1l, w1T, 1024, 4096);
        transpose_w<<<dim3(1024 / 32, 4096 / 32), 256, 0, stream>>>(w2l, w2T, 4096, 1024);

        cat_kernel<<<4096, 256, 0, stream>>>(mems + (size_t)l * 2048 * 1024, h, catb);

        gemm_bt<0><<<dim3(3072 / 128, 4096 / 128), 256, 0, stream>>>(
            catb, qkvT, wheads, nullptr, nullptr, 4096, 3072, 1024);
        scatter_qkv<<<4096, 256, 0, stream>>>(wheads, rwb + l * 1024, rrb + l * 1024,
                                              Qw, Qr, Kb, VTb);

        gemm_bt<0><<<dim3(1024 / 128, 1024 / 128), 256, 0, stream>>>(
            posb, rT, rkf, nullptr, nullptr, 1024, 1024, 1024);
        scatter_rk<<<1024, 256, 0, stream>>>(rkf, Rb);

        attn_kernel<<<512, 256, 0, stream>>>(Qw, Qr, Kb, VTb, Rb, avec);

        gemm_bt<0><<<dim3(1024 / 128, 2048 / 128), 256, 0, stream>>>(
            avec, oT, resid, nullptr, nullptr, 2048, 1024, 1024);
        ln_kernel<<<2048, 256, 0, stream>>>(h, resid, ln1g + l * 1024, ln1b + l * 1024, h, hbf);

        gemm_bt<1><<<dim3(4096 / 128, 2048 / 128), 256, 0, stream>>>(
            hbf, w1T, nullptr, ff1b, ffb1 + l * 4096, 2048, 4096, 1024);
        gemm_bt<2><<<dim3(1024 / 128, 2048 / 128), 256, 0, stream>>>(
            ff1b, w2T, resid, nullptr, ffb2 + l * 1024, 2048, 1024, 4096);
        ln_kernel<<<2048, 256, 0, stream>>>(h, resid, ln2g + l * 1024, ln2b + l * 1024, h, hbf);
    }

    out_kernel<<<2048, 256, 0, stream>>>(h, (float*)d_out);
}

// Round 2
// 1478.036 us; speedup vs baseline: 1.9539x; 1.9539x over previous
//
#include <hip/hip_runtime.h>

typedef __attribute__((ext_vector_type(8))) short bf16x8;
typedef __attribute__((ext_vector_type(4))) float f32x4;

#define N_LAYER 4
#define QLEN 512
#define MLEN 512
#define KLEN 1024
#define BSZ 4
#define DM 1024
#define NH 16
#define DH 64
#define DINNER 4096
#define EK 1408  // padded adaptive-emb K: 1024 + 256 + 64 + 64(pad from 16)

__device__ __forceinline__ unsigned short f2bf(float x) {
    unsigned u = __float_as_uint(x);
    u += 0x7fffu + ((u >> 16) & 1u);
    return (unsigned short)(u >> 16);
}
__device__ __forceinline__ float bf2f(unsigned short v) {
    return __uint_as_float(((unsigned)v) << 16);
}

__device__ __forceinline__ void gload16(const unsigned short* g, unsigned short* l) {
    __builtin_amdgcn_global_load_lds(
        (const __attribute__((address_space(1))) unsigned int*)g,
        (__attribute__((address_space(3))) unsigned int*)l, 16, 0, 0);
}

// ---------------------------------------------------------------------------
// Weight transpose + f32->bf16:  W (K x N) -> WT (N x K) bf16
// ---------------------------------------------------------------------------
__global__ __launch_bounds__(256)
void transpose_w(const float* __restrict__ W, unsigned short* __restrict__ WT,
                 int K, int N) {
    __shared__ float tile[32][33];
    const int tx = threadIdx.x & 31, ty = threadIdx.x >> 5;
    const int bx = blockIdx.x, by = blockIdx.y;
#pragma unroll
    for (int i = 0; i < 4; ++i)
        tile[ty + i * 8][tx] = W[(size_t)(by * 32 + ty + i * 8) * N + bx * 32 + tx];
    __syncthreads();
#pragma unroll
    for (int i = 0; i < 4; ++i)
        WT[(size_t)(bx * 32 + ty + i * 8) * K + by * 32 + tx] = f2bf(tile[tx][ty + i * 8]);
}

// Transpose with zero-padding beyond K rows, into a slice of a wider dst row.
__global__ __launch_bounds__(256)
void transpose_pad(const float* __restrict__ W, unsigned short* __restrict__ dst,
                   int K, int N, int dstLD, int dstOff) {
    __shared__ float tile[32][33];
    const int tx = threadIdx.x & 31, ty = threadIdx.x >> 5;
    const int bx = blockIdx.x, by = blockIdx.y;
#pragma unroll
    for (int i = 0; i < 4; ++i) {
        int k = by * 32 + ty + i * 8;
        tile[ty + i * 8][tx] = (k < K) ? W[(size_t)k * N + bx * 32 + tx] : 0.f;
    }
    __syncthreads();
#pragma unroll
    for (int i = 0; i < 4; ++i) {
        int n = bx * 32 + ty + i * 8;
        int k = by * 32 + tx;
        dst[(size_t)n * dstLD + dstOff + k] = f2bf(tile[tx][ty + i * 8]);
    }
}

// ---------------------------------------------------------------------------
// Adaptive-embedding gather: embA[t][0:1408) = masked cluster row * 32, bf16
// ---------------------------------------------------------------------------
__global__ __launch_bounds__(256)
void emb_gather(const int* __restrict__ ids,
                const float* __restrict__ e0, const float* __restrict__ e1,
                const float* __restrict__ e2, const float* __restrict__ e3,
                unsigned short* __restrict__ embA) {
    const int chunk = blockIdx.x * 256 + threadIdx.x;
    if (chunk >= 2048 * 176) return;
    const int t = chunk / 176;
    const int e8 = (chunk - t * 176) * 8;
    const int i = t >> 2, b = t & 3;
    const int id = ids[b * QLEN + i];
    const float* src = nullptr;
    if (e8 < 1024) {
        if (id < 20000) src = e0 + (size_t)id * 1024 + e8;
    } else if (e8 < 1280) {
        if (id >= 20000 && id < 40000) src = e1 + (size_t)(id - 20000) * 256 + (e8 - 1024);
    } else if (e8 < 1344) {
        if (id >= 40000 && id < 200000) src = e2 + (size_t)(id - 40000) * 64 + (e8 - 1280);
    } else if (e8 < 1360) {
        if (id >= 200000) src = e3 + (size_t)(id - 200000) * 16 + (e8 - 1344);
    }
    uint4 o = {0u, 0u, 0u, 0u};
    if (src) {
        float4 v0 = *(const float4*)src;
        float4 v1 = *(const float4*)(src + 4);
        o.x = (unsigned)f2bf(v0.x * 32.f) | ((unsigned)f2bf(v0.y * 32.f) << 16);
        o.y = (unsigned)f2bf(v0.z * 32.f) | ((unsigned)f2bf(v0.w * 32.f) << 16);
        o.z = (unsigned)f2bf(v1.x * 32.f) | ((unsigned)f2bf(v1.y * 32.f) << 16);
        o.w = (unsigned)f2bf(v1.z * 32.f) | ((unsigned)f2bf(v1.w * 32.f) << 16);
    }
    *(uint4*)(embA + (size_t)t * EK + e8) = o;
}

// ---------------------------------------------------------------------------
// GEMM: C[M,N] = A[M,K] @ B[K,N], A bf16 row-major, BT = B^T bf16 (N x K)
// m97 structure: global_load_lds width-16 staging, 2 barriers per K-step.
// MODE 0: C f32. MODE 1: Cbf = bf16(relu(acc+bias)). MODE 2: C = acc+bias.
// MODE 3: QKV scatter epilogue. MODE 4: r_head_k scatter epilogue.
// ---------------------------------------------------------------------------
template <int MODE>
__global__ __launch_bounds__(256)
void gemm_bt(const unsigned short* __restrict__ A, const unsigned short* __restrict__ BT,
             float* __restrict__ C, unsigned short* __restrict__ Cbf,
             const float* __restrict__ bias,
             const float* __restrict__ rwb, const float* __restrict__ rrb,
             unsigned short* __restrict__ Qw, unsigned short* __restrict__ Qr,
             unsigned short* __restrict__ Kb, unsigned short* __restrict__ VTb,
             int M, int N, int K) {
    __shared__ unsigned short lA[128 * 64];
    __shared__ unsigned short lB[128 * 64];
    const int tid = threadIdx.x;
    const int w = tid >> 6, l = tid & 63;
    const int lane15 = l & 15, lh = l >> 4;
    const int bm = blockIdx.y, bn = blockIdx.x;
    const int wr = (w >> 1) * 64, wc = (w & 1) * 64;

    f32x4 acc[4][4] = {};

    const int srow = tid >> 3;         // 0..31
    const int scol = (tid & 7) * 8;    // 0..56
    const unsigned short* gA = A + (size_t)(bm * 128 + srow) * K + scol;
    const unsigned short* gB = BT + (size_t)(bn * 128 + srow) * K + scol;
    unsigned short* lAp = lA + tid * 8;  // linear: lane-contiguous 16B
    unsigned short* lBp = lB + tid * 8;

    for (int k0 = 0; k0 < K; k0 += 64) {
        __syncthreads();
#pragma unroll
        for (int it = 0; it < 4; ++it) {
            gload16(gA + (size_t)(it * 32) * K + k0, lAp + it * 2048);
            gload16(gB + (size_t)(it * 32) * K + k0, lBp + it * 2048);
        }
        __syncthreads();
#pragma unroll
        for (int kk = 0; kk < 2; ++kk) {
            bf16x8 af[4], bfr[4];
#pragma unroll
            for (int f = 0; f < 4; ++f) {
                af[f]  = *(const bf16x8*)(lA + (wr + f * 16 + lane15) * 64 + kk * 32 + lh * 8);
                bfr[f] = *(const bf16x8*)(lB + (wc + f * 16 + lane15) * 64 + kk * 32 + lh * 8);
            }
#pragma unroll
            for (int mi = 0; mi < 4; ++mi)
#pragma unroll
                for (int ni = 0; ni < 4; ++ni)
                    acc[mi][ni] = __builtin_amdgcn_mfma_f32_16x16x32_bf16(
                        af[mi], bfr[ni], acc[mi][ni], 0, 0, 0);
        }
    }

#pragma unroll
    for (int mi = 0; mi < 4; ++mi) {
        int rowb = bm * 128 + wr + mi * 16 + lh * 4;   // multiple of 4
#pragma unroll
        for (int ni = 0; ni < 4; ++ni) {
            int col = bn * 128 + wc + ni * 16 + lane15;
#pragma unroll
            for (int r = 0; r < 4; ++r) {
                float x = acc[mi][ni][r];
                if (MODE == 0) {
                    C[(size_t)(rowb + r) * N + col] = x;
                } else if (MODE == 1) {
                    x += bias[col];
                    Cbf[(size_t)(rowb + r) * N + col] = f2bf(x > 0.f ? x : 0.f);
                } else if (MODE == 2) {
                    C[(size_t)(rowb + r) * N + col] = x + bias[col];
                } else if (MODE == 3) {
                    // row t = rowb + r; j = t>>2, b = r  (rowb % 4 == 0)
                    int j = rowb >> 2;
                    int bb_ = r;
                    if (col < 1024) {
                        if (j >= MLEN) {
                            int i = j - MLEN, n = col >> 6, d = col & 63;
                            size_t o = ((size_t)(bb_ * NH + n) * QLEN + i) * DH + d;
                            Qw[o] = f2bf(x + rwb[col]);
                            Qr[o] = f2bf(x + rrb[col]);
                        }
                    } else if (col < 2048) {
                        int c2 = col - 1024, n = c2 >> 6, d = c2 & 63;
                        Kb[((size_t)(bb_ * NH + n) * KLEN + j) * DH + d] = f2bf(x);
                    } else {
                        int c2 = col - 2048, n = c2 >> 6, d = c2 & 63;
                        VTb[((size_t)(bb_ * NH + n) * DH + d) * KLEN + j] = f2bf(x);
                    }
                } else { // MODE 4: rows are j in [0,1024), cols n*64+d
                    int j = rowb + r;
                    int n = col >> 6, d = col & 63;
                    Kb[((size_t)n * KLEN + j) * DH + d] = f2bf(x);  // Kb := Rb here
                }
            }
        }
    }
}

// ---------------------------------------------------------------------------
// Positional embedding table (1024 x 1024), bf16
// ---------------------------------------------------------------------------
__global__ __launch_bounds__(256)
void pos_kernel(unsigned short* __restrict__ posbf) {
    const int p = blockIdx.x, tid = threadIdx.x;
    const float ps = (float)(KLEN - 1 - p);
    const float c = -2.0f * 9.210340371976184f / 1024.0f; // -2*ln(10000)/D
#pragma unroll
    for (int j4 = 0; j4 < 4; ++j4) {
        int j = tid + j4 * 256;
        int m = (j < 512) ? j : j - 512;
        float freq = __expf((float)m * c);
        float ang = ps * freq;
        float v = (j < 512) ? sinf(ang) : cosf(ang);
        posbf[(size_t)p * DM + j] = f2bf(v);
    }
}

// ---------------------------------------------------------------------------
// cat = [mems_l ; h] -> bf16 (4096 x 1024)
// ---------------------------------------------------------------------------
__global__ __launch_bounds__(256)
void cat_kernel(const float* __restrict__ mem_l, const float* __restrict__ h,
                unsigned short* __restrict__ catbf) {
    const int t = blockIdx.x, tid = threadIdx.x;
    const float* src = (t < 2048) ? (mem_l + (size_t)t * DM) : (h + (size_t)(t - 2048) * DM);
    float4 v = ((const float4*)src)[tid];
    uint2 o;
    o.x = (unsigned)f2bf(v.x) | ((unsigned)f2bf(v.y) << 16);
    o.y = (unsigned)f2bf(v.z) | ((unsigned)f2bf(v.w) << 16);
    ((uint2*)(catbf + (size_t)t * DM))[tid] = o;
}

// ---------------------------------------------------------------------------
// Fused rel-attention, flash style. Block = (b, n, 64-row i-tile), 4 waves.
// ---------------------------------------------------------------------------
__global__ __launch_bounds__(256)
void attn_kernel(const unsigned short* __restrict__ Qw, const unsigned short* __restrict__ Qr,
                 const unsigned short* __restrict__ Kb, const unsigned short* __restrict__ VTb,
                 const unsigned short* __restrict__ Rb, unsigned short* __restrict__ avec) {
    __shared__ unsigned short lK[64 * 64];
    __shared__ unsigned short lVT[64 * 64];
    __shared__ unsigned short lR[128 * 64];
    __shared__ unsigned short lBD[4][16 * 128];
    __shared__ unsigned short lP[4][16 * 64];

    const int tid = threadIdx.x;
    const int w = tid >> 6, l = tid & 63;
    const int lane15 = l & 15, lh = l >> 4;
    const int blk = blockIdx.x;
    const int it = blk & 7;
    const int bn = blk >> 3;          // b*16 + n
    const int n = bn & 15, b = bn >> 4;
    const int i0 = it * 64;
    const int rowl = w * 16 + lh * 4;

    bf16x8 qw[2], qr[2];
    {
        size_t base = ((size_t)bn * QLEN + i0 + w * 16 + lane15) * DH + lh * 8;
        qw[0] = *(const bf16x8*)(Qw + base);
        qw[1] = *(const bf16x8*)(Qw + base + 32);
        qr[0] = *(const bf16x8*)(Qr + base);
        qr[1] = *(const bf16x8*)(Qr + base + 32);
    }

    f32x4 oacc[4] = {};
    float mrow[4], srow[4];
#pragma unroll
    for (int r = 0; r < 4; ++r) { mrow[r] = -1e30f; srow[r] = 0.f; }

    const int ntiles = it + 9;
    for (int jt = 0; jt < ntiles; ++jt) {
        const int j0 = jt * 64;
        const int rbase = 448 + (jt - it) * 64;
        __syncthreads();
        {
            const uint4* sK = (const uint4*)(Kb + ((size_t)bn * KLEN + j0) * DH);
            ((uint4*)lK)[tid] = sK[tid];
            ((uint4*)lK)[tid + 256] = sK[tid + 256];
#pragma unroll
            for (int s = 0; s < 2; ++s) {
                int idx = s * 256 + tid;
                int d = idx >> 3, c = (idx & 7) * 8;
                *(uint4*)(lVT + d * 64 + c) =
                    *(const uint4*)(VTb + ((size_t)bn * DH + d) * KLEN + j0 + c);
            }
#pragma unroll
            for (int s = 0; s < 4; ++s) {
                int idx = s * 256 + tid;
                int rl = idx >> 3, c = (idx & 7) * 8;
                int rr = rbase + rl; if (rr > 1023) rr = 1023;
                *(uint4*)(lR + rl * 64 + c) =
                    *(const uint4*)(Rb + ((size_t)n * KLEN + rr) * DH + c);
            }
        }
        __syncthreads();

        f32x4 sac[4] = {};
        f32x4 bd[8] = {};
#pragma unroll
        for (int kk = 0; kk < 2; ++kk) {
#pragma unroll
            for (int f = 0; f < 4; ++f) {
                bf16x8 kb = *(const bf16x8*)(lK + (f * 16 + lane15) * 64 + kk * 32 + lh * 8);
                sac[f] = __builtin_amdgcn_mfma_f32_16x16x32_bf16(qw[kk], kb, sac[f], 0, 0, 0);
            }
#pragma unroll
            for (int f = 0; f < 8; ++f) {
                bf16x8 rb = *(const bf16x8*)(lR + (f * 16 + lane15) * 64 + kk * 32 + lh * 8);
                bd[f] = __builtin_amdgcn_mfma_f32_16x16x32_bf16(qr[kk], rb, bd[f], 0, 0, 0);
            }
        }
#pragma unroll
        for (int f = 0; f < 8; ++f)
#pragma unroll
            for (int r = 0; r < 4; ++r)
                lBD[w][(lh * 4 + r) * 128 + lane15 + 16 * f] = f2bf(bd[f][r]);

        float pv[4][4];
        float tmax[4] = {-1e30f, -1e30f, -1e30f, -1e30f};
        const bool lastTile = (jt == it + 8);
#pragma unroll
        for (int f = 0; f < 4; ++f) {
            int lj = lane15 + 16 * f;
#pragma unroll
            for (int r = 0; r < 4; ++r) {
                int li = rowl + r;
                float bdv = bf2f(lBD[w][(lh * 4 + r) * 128 + (63 + lj - li)]);
                float s = (sac[f][r] + bdv) * 0.125f;
                if (lastTile && (lj > li)) s = -1e30f;
                pv[f][r] = s;
                tmax[r] = fmaxf(tmax[r], s);
            }
        }
#pragma unroll
        for (int off = 1; off < 16; off <<= 1)
#pragma unroll
            for (int r = 0; r < 4; ++r)
                tmax[r] = fmaxf(tmax[r], __shfl_xor(tmax[r], off));

        float scal[4], tsum[4];
#pragma unroll
        for (int r = 0; r < 4; ++r) {
            float nm = fmaxf(mrow[r], tmax[r]);
            scal[r] = __expf(mrow[r] - nm);
            mrow[r] = nm;
            float ts = 0.f;
#pragma unroll
            for (int f = 0; f < 4; ++f) {
                float e = __expf(pv[f][r] - nm);
                pv[f][r] = e;
                ts += e;
            }
            tsum[r] = ts;
        }
#pragma unroll
        for (int off = 1; off < 16; off <<= 1)
#pragma unroll
            for (int r = 0; r < 4; ++r)
                tsum[r] += __shfl_xor(tsum[r], off);
#pragma unroll
        for (int r = 0; r < 4; ++r) {
            srow[r] = srow[r] * scal[r] + tsum[r];
#pragma unroll
            for (int f = 0; f < 4; ++f) oacc[f][r] *= scal[r];
        }
#pragma unroll
        for (int f = 0; f < 4; ++f)
#pragma unroll
            for (int r = 0; r < 4; ++r)
                lP[w][(lh * 4 + r) * 64 + lane15 + 16 * f] = f2bf(pv[f][r]);
#pragma unroll
        for (int kk = 0; kk < 2; ++kk) {
            bf16x8 pa = *(const bf16x8*)(&lP[w][lane15 * 64 + kk * 32 + lh * 8]);
#pragma unroll
            for (int f = 0; f < 4; ++f) {
                bf16x8 vb = *(const bf16x8*)(lVT + (f * 16 + lane15) * 64 + kk * 32 + lh * 8);
                oacc[f] = __builtin_amdgcn_mfma_f32_16x16x32_bf16(pa, vb, oacc[f], 0, 0, 0);
            }
        }
    }

#pragma unroll
    for (int f = 0; f < 4; ++f)
#pragma unroll
        for (int r = 0; r < 4; ++r) {
            int i = i0 + rowl + r;
            int t = i * 4 + b;
            int col = n * 64 + lane15 + 16 * f;
            avec[(size_t)t * DM + col] = f2bf(oacc[f][r] / srow[r]);
        }
}

// ---------------------------------------------------------------------------
// LayerNorm: h = LN(hin + res) * g + b ; emits f32 h and bf16 h
// ---------------------------------------------------------------------------
__global__ __launch_bounds__(256)
void ln_kernel(const float* __restrict__ hin, const float* __restrict__ res,
               const float* __restrict__ g, const float* __restrict__ bb,
               float* __restrict__ hout, unsigned short* __restrict__ hbf) {
    __shared__ float ls[8];
    const int t = blockIdx.x, tid = threadIdx.x;
    float4 x = ((const float4*)(hin + (size_t)t * DM))[tid];
    float4 rr = ((const float4*)(res + (size_t)t * DM))[tid];
    float v0 = x.x + rr.x, v1 = x.y + rr.y, v2 = x.z + rr.z, v3 = x.w + rr.w;
    float s = v0 + v1 + v2 + v3;
    float sq = v0 * v0 + v1 * v1 + v2 * v2 + v3 * v3;
#pragma unroll
    for (int off = 1; off < 64; off <<= 1) {
        s += __shfl_xor(s, off);
        sq += __shfl_xor(sq, off);
    }
    const int w = tid >> 6;
    if ((tid & 63) == 0) { ls[w] = s; ls[4 + w] = sq; }
    __syncthreads();
    s = ls[0] + ls[1] + ls[2] + ls[3];
    sq = ls[4] + ls[5] + ls[6] + ls[7];
    float mu = s * (1.f / 1024.f);
    float var = sq * (1.f / 1024.f) - mu * mu;
    float rstd = rsqrtf(var + 1e-5f);
    float y[4] = {v0, v1, v2, v3};
    float4 of;
    uint2 ob;
    float* op = &of.x;
#pragma unroll
    for (int j = 0; j < 4; ++j) {
        int d = tid * 4 + j;
        op[j] = (y[j] - mu) * rstd * g[d] + bb[d];
    }
    ob.x = (unsigned)f2bf(of.x) | ((unsigned)f2bf(of.y) << 16);
    ob.y = (unsigned)f2bf(of.z) | ((unsigned)f2bf(of.w) << 16);
    ((float4*)(hout + (size_t)t * DM))[tid] = of;
    ((uint2*)(hbf + (size_t)t * DM))[tid] = ob;
}

__global__ __launch_bounds__(256)
void out_kernel(const float* __restrict__ h, float* __restrict__ out) {
    const int t = blockIdx.x, tid = threadIdx.x;
    const int i = t >> 2, b = t & 3;
    ((float4*)(out + ((size_t)b * QLEN + i) * DM))[tid] =
        ((const float4*)(h + (size_t)t * DM))[tid];
}

// ---------------------------------------------------------------------------
extern "C" void kernel_launch(void* const* d_in, const int* in_sizes, int n_in,
                              void* d_out, int out_size, void* d_ws, size_t ws_size,
                              hipStream_t stream) {
    const int* ids = (const int*)d_in[0];
    const float* mems = (const float*)d_in[1];
    const float* embp[4] = {nullptr, nullptr, nullptr, nullptr};
    const float* projp[4] = {nullptr, nullptr, nullptr, nullptr};
    const long long esz[4] = {20000LL * 1024, 20000LL * 256, 160000LL * 64, 67735LL * 16};
    const long long psz[4] = {1024LL * 1024, 256LL * 1024, 64LL * 1024, 16LL * 1024};
    for (int idx = 2; idx <= 9 && idx < n_in; ++idx) {
        long long s = in_sizes[idx];
        for (int c = 0; c < 4; ++c) {
            if (s == esz[c]) embp[c] = (const float*)d_in[idx];
            else if (s == psz[c]) projp[c] = (const float*)d_in[idx];
        }
    }
    const float* qkvW = (const float*)d_in[10];
    const float* rW   = (const float*)d_in[11];
    const float* oW   = (const float*)d_in[12];
    const float* rwb  = (const float*)d_in[13];
    const float* rrb  = (const float*)d_in[14];
    const float* ln1g = (const float*)d_in[15];
    const float* ln1b = (const float*)d_in[16];
    const float* ffw1 = (const float*)d_in[17];
    const float* ffb1 = (const float*)d_in[18];
    const float* ffw2 = (const float*)d_in[19];
    const float* ffb2 = (const float*)d_in[20];
    const float* ln2g = (const float*)d_in[21];
    const float* ln2b = (const float*)d_in[22];

    size_t off = 0;
    char* base = (char*)d_ws;
    auto alloc = [&](size_t bytes) -> char* {
        char* p = base + off;
        off = (off + bytes + 255) & ~(size_t)255;
        return p;
    };
    unsigned short* qkvT  = (unsigned short*)alloc(3072ull * 1024 * 2);
    unsigned short* rT    = (unsigned short*)alloc(1024ull * 1024 * 2);
    unsigned short* oT    = (unsigned short*)alloc(1024ull * 1024 * 2);
    unsigned short* w1T   = (unsigned short*)alloc(4096ull * 1024 * 2);
    unsigned short* w2T   = (unsigned short*)alloc(1024ull * 4096 * 2);
    unsigned short* embA  = (unsigned short*)alloc(2048ull * EK * 2);
    unsigned short* embBT = (unsigned short*)alloc(1024ull * EK * 2);
    float* h              = (float*)alloc(2048ull * 1024 * 4);
    unsigned short* hbf   = (unsigned short*)alloc(2048ull * 1024 * 2);
    unsigned short* catb  = (unsigned short*)alloc(4096ull * 1024 * 2);
    unsigned short* posb  = (unsigned short*)alloc(1024ull * 1024 * 2);
    unsigned short* Qw    = (unsigned short*)alloc(4ull * 16 * 512 * 64 * 2);
    unsigned short* Qr    = (unsigned short*)alloc(4ull * 16 * 512 * 64 * 2);
    unsigned short* Kb    = (unsigned short*)alloc(4ull * 16 * 1024 * 64 * 2);
    unsigned short* VTb   = (unsigned short*)alloc(4ull * 16 * 1024 * 64 * 2);
    unsigned short* Rb    = (unsigned short*)alloc(16ull * 1024 * 64 * 2);
    unsigned short* avec  = (unsigned short*)alloc(2048ull * 1024 * 2);
    float* resid          = (float*)alloc(2048ull * 1024 * 4);
    unsigned short* ff1b  = (unsigned short*)alloc(2048ull * 4096 * 2);
    (void)ws_size; (void)out_size;

    // ---- embeddings (gather + GEMM) + positional table ----
    emb_gather<<<(2048 * 176 + 255) / 256, 256, 0, stream>>>(
        ids, embp[0], embp[1], embp[2], embp[3], embA);
    transpose_pad<<<dim3(32, 32), 256, 0, stream>>>(projp[0], embBT, 1024, 1024, EK, 0);
    transpose_pad<<<dim3(32, 8),  256, 0, stream>>>(projp[1], embBT, 256,  1024, EK, 1024);
    transpose_pad<<<dim3(32, 2),  256, 0, stream>>>(projp[2], embBT, 64,   1024, EK, 1280);
    transpose_pad<<<dim3(32, 2),  256, 0, stream>>>(projp[3], embBT, 16,   1024, EK, 1344);
    pos_kernel<<<1024, 256, 0, stream>>>(posb);
    gemm_bt<0><<<dim3(1024 / 128, 2048 / 128), 256, 0, stream>>>(
        embA, embBT, h, nullptr, nullptr, nullptr, nullptr, nullptr, nullptr, nullptr, nullptr,
        2048, 1024, EK);

    for (int l = 0; l < N_LAYER; ++l) {
        const float* qkvWl = qkvW + (size_t)l * 1024 * 3072;
        const float* rWl   = rW + (size_t)l * 1024 * 1024;
        const float* oWl   = oW + (size_t)l * 1024 * 1024;
        const float* w1l   = ffw1 + (size_t)l * 1024 * 4096;
        const float* w2l   = ffw2 + (size_t)l * 4096 * 1024;

        transpose_w<<<dim3(3072 / 32, 1024 / 32), 256, 0, stream>>>(qkvWl, qkvT, 1024, 3072);
        transpose_w<<<dim3(1024 / 32, 1024 / 32), 256, 0, stream>>>(rWl, rT, 1024, 1024);
        transpose_w<<<dim3(1024 / 32, 1024 / 32), 256, 0, stream>>>(oWl, oT, 1024, 1024);
        transpose_w<<<dim3(4096 / 32, 1024 / 32), 256, 0, stream>>>(w1l, w1T, 1024, 4096);
        transpose_w<<<dim3(1024 / 32, 4096 / 32), 256, 0, stream>>>(w2l, w2T, 4096, 1024);

        cat_kernel<<<4096, 256, 0, stream>>>(mems + (size_t)l * 2048 * 1024, h, catb);

        // QKV GEMM with fused scatter (+rel biases)
        gemm_bt<3><<<dim3(3072 / 128, 4096 / 128), 256, 0, stream>>>(
            catb, qkvT, nullptr, nullptr, nullptr,
            rwb + l * 1024, rrb + l * 1024, Qw, Qr, Kb, VTb, 4096, 3072, 1024);

        // r_head_k GEMM with fused scatter -> Rb
        gemm_bt<4><<<dim3(1024 / 128, 1024 / 128), 256, 0, stream>>>(
            posb, rT, nullptr, nullptr, nullptr,
            nullptr, nullptr, nullptr, nullptr, Rb, nullptr, 1024, 1024, 1024);

        attn_kernel<<<512, 256, 0, stream>>>(Qw, Qr, Kb, VTb, Rb, avec);

        gemm_bt<0><<<dim3(1024 / 128, 2048 / 128), 256, 0, stream>>>(
            avec, oT, resid, nullptr, nullptr, nullptr, nullptr, nullptr, nullptr, nullptr, nullptr,
            2048, 1024, 1024);
        ln_kernel<<<2048, 256, 0, stream>>>(h, resid, ln1g + l * 1024, ln1b + l * 1024, h, hbf);

        gemm_bt<1><<<dim3(4096 / 128, 2048 / 128), 256, 0, stream>>>(
            hbf, w1T, nullptr, ff1b, ffb1 + l * 4096, nullptr, nullptr, nullptr, nullptr, nullptr, nullptr,
            2048, 4096, 1024);
        gemm_bt<2><<<dim3(1024 / 128, 2048 / 128), 256, 0, stream>>>(
            ff1b, w2T, resid, nullptr, ffb2 + l * 1024, nullptr, nullptr, nullptr, nullptr, nullptr, nullptr,
            2048, 1024, 4096);
        ln_kernel<<<2048, 256, 0, stream>>>(h, resid, ln2g + l * 1024, ln2b + l * 1024, h, hbf);
    }

    out_kernel<<<2048, 256, 0, stream>>>(h, (float*)d_out);
}

// Round 3
// 1345.755 us; speedup vs baseline: 2.1459x; 1.0983x over previous
//
#include <hip/hip_runtime.h>

typedef __attribute__((ext_vector_type(8))) short bf16x8;
typedef __attribute__((ext_vector_type(4))) float f32x4;

#define N_LAYER 4
#define QLEN 512
#define MLEN 512
#define KLEN 1024
#define BSZ 4
#define DM 1024
#define NH 16
#define DH 64
#define DINNER 4096
#define EK 1408  // padded adaptive-emb K: 1024 + 256 + 64 + 64(pad from 16)

__device__ __forceinline__ unsigned short f2bf(float x) {
    unsigned u = __float_as_uint(x);
    u += 0x7fffu + ((u >> 16) & 1u);
    return (unsigned short)(u >> 16);
}
__device__ __forceinline__ float bf2f(unsigned short v) {
    return __uint_as_float(((unsigned)v) << 16);
}

__device__ __forceinline__ void gload16(const unsigned short* g, unsigned short* l) {
    __builtin_amdgcn_global_load_lds(
        (const __attribute__((address_space(1))) unsigned int*)g,
        (__attribute__((address_space(3))) unsigned int*)l, 16, 0, 0);
}

// swizzled b128 LDS read for 128B-row-stride bf16 tiles: byte ^= (row&7)<<4
__device__ __forceinline__ bf16x8 lds_read8_sw(const unsigned short* base, int row, int cb) {
    return *(const bf16x8*)((const char*)base + row * 128 + (cb ^ ((row & 7) << 4)));
}

// ---------------------------------------------------------------------------
// Weight transpose + f32->bf16:  W (K x N) -> WT (N x K) bf16
// ---------------------------------------------------------------------------
__global__ __launch_bounds__(256)
void transpose_w(const float* __restrict__ W, unsigned short* __restrict__ WT,
                 int K, int N) {
    __shared__ float tile[32][33];
    const int tx = threadIdx.x & 31, ty = threadIdx.x >> 5;
    const int bx = blockIdx.x, by = blockIdx.y;
#pragma unroll
    for (int i = 0; i < 4; ++i)
        tile[ty + i * 8][tx] = W[(size_t)(by * 32 + ty + i * 8) * N + bx * 32 + tx];
    __syncthreads();
#pragma unroll
    for (int i = 0; i < 4; ++i)
        WT[(size_t)(bx * 32 + ty + i * 8) * K + by * 32 + tx] = f2bf(tile[tx][ty + i * 8]);
}

// Transpose with zero-padding beyond K rows, into a slice of a wider dst row.
__global__ __launch_bounds__(256)
void transpose_pad(const float* __restrict__ W, unsigned short* __restrict__ dst,
                   int K, int N, int dstLD, int dstOff) {
    __shared__ float tile[32][33];
    const int tx = threadIdx.x & 31, ty = threadIdx.x >> 5;
    const int bx = blockIdx.x, by = blockIdx.y;
#pragma unroll
    for (int i = 0; i < 4; ++i) {
        int k = by * 32 + ty + i * 8;
        tile[ty + i * 8][tx] = (k < K) ? W[(size_t)k * N + bx * 32 + tx] : 0.f;
    }
    __syncthreads();
#pragma unroll
    for (int i = 0; i < 4; ++i) {
        int n = bx * 32 + ty + i * 8;
        int k = by * 32 + tx;
        dst[(size_t)n * dstLD + dstOff + k] = f2bf(tile[tx][ty + i * 8]);
    }
}

// ---------------------------------------------------------------------------
// Adaptive-embedding gather: embA[t][0:1408) = masked cluster row * 32, bf16
// ---------------------------------------------------------------------------
__global__ __launch_bounds__(256)
void emb_gather(const int* __restrict__ ids,
                const float* __restrict__ e0, const float* __restrict__ e1,
                const float* __restrict__ e2, const float* __restrict__ e3,
                unsigned short* __restrict__ embA) {
    const int chunk = blockIdx.x * 256 + threadIdx.x;
    if (chunk >= 2048 * 176) return;
    const int t = chunk / 176;
    const int e8 = (chunk - t * 176) * 8;
    const int i = t >> 2, b = t & 3;
    const int id = ids[b * QLEN + i];
    const float* src = nullptr;
    if (e8 < 1024) {
        if (id < 20000) src = e0 + (size_t)id * 1024 + e8;
    } else if (e8 < 1280) {
        if (id >= 20000 && id < 40000) src = e1 + (size_t)(id - 20000) * 256 + (e8 - 1024);
    } else if (e8 < 1344) {
        if (id >= 40000 && id < 200000) src = e2 + (size_t)(id - 40000) * 64 + (e8 - 1280);
    } else if (e8 < 1360) {
        if (id >= 200000) src = e3 + (size_t)(id - 200000) * 16 + (e8 - 1344);
    }
    uint4 o = {0u, 0u, 0u, 0u};
    if (src) {
        float4 v0 = *(const float4*)src;
        float4 v1 = *(const float4*)(src + 4);
        o.x = (unsigned)f2bf(v0.x * 32.f) | ((unsigned)f2bf(v0.y * 32.f) << 16);
        o.y = (unsigned)f2bf(v0.z * 32.f) | ((unsigned)f2bf(v0.w * 32.f) << 16);
        o.z = (unsigned)f2bf(v1.x * 32.f) | ((unsigned)f2bf(v1.y * 32.f) << 16);
        o.w = (unsigned)f2bf(v1.z * 32.f) | ((unsigned)f2bf(v1.w * 32.f) << 16);
    }
    *(uint4*)(embA + (size_t)t * EK + e8) = o;
}

// ---------------------------------------------------------------------------
// GEMM: C[M,N] = A[M,K] @ B[K,N], A bf16 row-major, BT = B^T bf16 (N x K)
// m97 structure + T2 swizzle (pre-swizzled global source, linear LDS dest).
// ---------------------------------------------------------------------------
template <int MODE>
__global__ __launch_bounds__(256)
void gemm_bt(const unsigned short* __restrict__ A, const unsigned short* __restrict__ BT,
             float* __restrict__ C, unsigned short* __restrict__ Cbf,
             const float* __restrict__ bias,
             const float* __restrict__ rwb, const float* __restrict__ rrb,
             unsigned short* __restrict__ Qw, unsigned short* __restrict__ Qr,
             unsigned short* __restrict__ Kb, unsigned short* __restrict__ VTb,
             int M, int N, int K) {
    __shared__ unsigned short lA[128 * 64];
    __shared__ unsigned short lB[128 * 64];
    const int tid = threadIdx.x;
    const int w = tid >> 6, l = tid & 63;
    const int lane15 = l & 15, lh = l >> 4;
    const int bm = blockIdx.y, bn = blockIdx.x;
    const int wr = (w >> 1) * 64, wc = (w & 1) * 64;

    f32x4 acc[4][4] = {};

    const int srow = tid >> 3;                       // 0..31
    const int scol = ((tid & 7) ^ (srow & 7)) * 8;   // inverse-swizzled source col
    const unsigned short* gA = A + (size_t)(bm * 128 + srow) * K + scol;
    const unsigned short* gB = BT + (size_t)(bn * 128 + srow) * K + scol;
    unsigned short* lAp = lA + tid * 8;  // linear LDS dest (lane-contiguous 16B)
    unsigned short* lBp = lB + tid * 8;

    for (int k0 = 0; k0 < K; k0 += 64) {
        __syncthreads();
#pragma unroll
        for (int it = 0; it < 4; ++it) {
            gload16(gA + (size_t)(it * 32) * K + k0, lAp + it * 2048);
            gload16(gB + (size_t)(it * 32) * K + k0, lBp + it * 2048);
        }
        __syncthreads();
#pragma unroll
        for (int kk = 0; kk < 2; ++kk) {
            bf16x8 af[4], bfr[4];
#pragma unroll
            for (int f = 0; f < 4; ++f) {
                af[f]  = lds_read8_sw(lA, wr + f * 16 + lane15, kk * 64 + lh * 16);
                bfr[f] = lds_read8_sw(lB, wc + f * 16 + lane15, kk * 64 + lh * 16);
            }
#pragma unroll
            for (int mi = 0; mi < 4; ++mi)
#pragma unroll
                for (int ni = 0; ni < 4; ++ni)
                    acc[mi][ni] = __builtin_amdgcn_mfma_f32_16x16x32_bf16(
                        af[mi], bfr[ni], acc[mi][ni], 0, 0, 0);
        }
    }

#pragma unroll
    for (int mi = 0; mi < 4; ++mi) {
        int rowb = bm * 128 + wr + mi * 16 + lh * 4;   // multiple of 4
#pragma unroll
        for (int ni = 0; ni < 4; ++ni) {
            int col = bn * 128 + wc + ni * 16 + lane15;
#pragma unroll
            for (int r = 0; r < 4; ++r) {
                float x = acc[mi][ni][r];
                if (MODE == 0) {
                    C[(size_t)(rowb + r) * N + col] = x;
                } else if (MODE == 1) {
                    x += bias[col];
                    Cbf[(size_t)(rowb + r) * N + col] = f2bf(x > 0.f ? x : 0.f);
                } else if (MODE == 2) {
                    C[(size_t)(rowb + r) * N + col] = x + bias[col];
                } else if (MODE == 3) {
                    int j = rowb >> 2;
                    int bb_ = r;
                    if (col < 1024) {
                        if (j >= MLEN) {
                            int i = j - MLEN, n = col >> 6, d = col & 63;
                            size_t o = ((size_t)(bb_ * NH + n) * QLEN + i) * DH + d;
                            Qw[o] = f2bf(x + rwb[col]);
                            Qr[o] = f2bf(x + rrb[col]);
                        }
                    } else if (col < 2048) {
                        int c2 = col - 1024, n = c2 >> 6, d = c2 & 63;
                        Kb[((size_t)(bb_ * NH + n) * KLEN + j) * DH + d] = f2bf(x);
                    } else {
                        int c2 = col - 2048, n = c2 >> 6, d = c2 & 63;
                        VTb[((size_t)(bb_ * NH + n) * DH + d) * KLEN + j] = f2bf(x);
                    }
                } else { // MODE 4
                    int j = rowb + r;
                    int n = col >> 6, d = col & 63;
                    Kb[((size_t)n * KLEN + j) * DH + d] = f2bf(x);  // Kb := Rb here
                }
            }
        }
    }
}

// ---------------------------------------------------------------------------
// Positional embedding table (1024 x 1024), bf16
// ---------------------------------------------------------------------------
__global__ __launch_bounds__(256)
void pos_kernel(unsigned short* __restrict__ posbf) {
    const int p = blockIdx.x, tid = threadIdx.x;
    const float ps = (float)(KLEN - 1 - p);
    const float c = -2.0f * 9.210340371976184f / 1024.0f; // -2*ln(10000)/D
#pragma unroll
    for (int j4 = 0; j4 < 4; ++j4) {
        int j = tid + j4 * 256;
        int m = (j < 512) ? j : j - 512;
        float freq = __expf((float)m * c);
        float ang = ps * freq;
        float v = (j < 512) ? sinf(ang) : cosf(ang);
        posbf[(size_t)p * DM + j] = f2bf(v);
    }
}

// ---------------------------------------------------------------------------
// cat = [mems_l ; h] -> bf16 (4096 x 1024)
// ---------------------------------------------------------------------------
__global__ __launch_bounds__(256)
void cat_kernel(const float* __restrict__ mem_l, const float* __restrict__ h,
                unsigned short* __restrict__ catbf) {
    const int t = blockIdx.x, tid = threadIdx.x;
    const float* src = (t < 2048) ? (mem_l + (size_t)t * DM) : (h + (size_t)(t - 2048) * DM);
    float4 v = ((const float4*)src)[tid];
    uint2 o;
    o.x = (unsigned)f2bf(v.x) | ((unsigned)f2bf(v.y) << 16);
    o.y = (unsigned)f2bf(v.z) | ((unsigned)f2bf(v.w) << 16);
    ((uint2*)(catbf + (size_t)t * DM))[tid] = o;
}

// ---------------------------------------------------------------------------
// Fused rel-attention, flash style. Block = (b, n, 64-row i-tile), 4 waves.
// XCD-local decode (bn = blk&63 -> same XCD for all i-tiles of a head),
// T2 XOR-swizzled LDS, T14 async staging, BD trimmed to the 5 used frags.
// ---------------------------------------------------------------------------
__global__ __launch_bounds__(256)
void attn_kernel(const unsigned short* __restrict__ Qw, const unsigned short* __restrict__ Qr,
                 const unsigned short* __restrict__ Kb, const unsigned short* __restrict__ VTb,
                 const unsigned short* __restrict__ Rb, unsigned short* __restrict__ avec) {
    __shared__ unsigned short lK[64 * 64];
    __shared__ unsigned short lVT[64 * 64];
    __shared__ unsigned short lR[2][64 * 64];   // sliding 2x64-row band halves
    __shared__ float lBD[4][16 * 83];           // per-wave BD band, stride 83 (bank spread)
    __shared__ unsigned short lP[4][16 * 64];

    const int tid = threadIdx.x;
    const int w = tid >> 6, l = tid & 63;
    const int lane15 = l & 15, lh = l >> 4;
    const int blk = blockIdx.x;
    const int bn = blk & 63;          // blk%8 == bn%8 -> all it of one head on one XCD
    const int it = blk >> 6;
    const int n = bn & 15, b = bn >> 4;
    const int i0 = it * 64;
    const int rowl = w * 16 + lh * 4;
    const int fbase = 3 - w;          // first used BD fragment for this wave

    // Q fragments (resident)
    bf16x8 qw[2], qr[2];
    {
        size_t base = ((size_t)bn * QLEN + i0 + w * 16 + lane15) * DH + lh * 8;
        qw[0] = *(const bf16x8*)(Qw + base);
        qw[1] = *(const bf16x8*)(Qw + base + 32);
        qr[0] = *(const bf16x8*)(Qr + base);
        qr[1] = *(const bf16x8*)(Qr + base + 32);
    }

    // staging: 2 granules/thread for one 64x64 bf16 tile
    auto ldK = [&](int j0, uint4* d) {
#pragma unroll
        for (int s = 0; s < 2; ++s) {
            int g = tid + s * 256;
            d[s] = *(const uint4*)(Kb + ((size_t)bn * KLEN + j0 + (g >> 3)) * DH + (g & 7) * 8);
        }
    };
    auto ldV = [&](int j0, uint4* d) {
#pragma unroll
        for (int s = 0; s < 2; ++s) {
            int g = tid + s * 256;
            d[s] = *(const uint4*)(VTb + ((size_t)bn * DH + (g >> 3)) * KLEN + j0 + (g & 7) * 8);
        }
    };
    auto ldR = [&](int rb0, uint4* d) {   // 64-row R block at abs base rb0, clamped
#pragma unroll
        for (int s = 0; s < 2; ++s) {
            int g = tid + s * 256;
            int rr = rb0 + (g >> 3); if (rr > 1023) rr = 1023;
            d[s] = *(const uint4*)(Rb + ((size_t)n * KLEN + rr) * DH + (g & 7) * 8);
        }
    };
    auto st64 = [&](unsigned short* basep, const uint4* d) {
#pragma unroll
        for (int s = 0; s < 2; ++s) {
            int g = tid + s * 256;
            int row = g >> 3, cb = (g & 7) * 16;
            *(uint4*)((char*)basep + row * 128 + (cb ^ ((row & 7) << 4))) = d[s];
        }
    };

    f32x4 oacc[4] = {};
    float mrow[4], srow[4];
#pragma unroll
    for (int r = 0; r < 4; ++r) { mrow[r] = -1e30f; srow[r] = 0.f; }

    const int ntiles = it + 9;

    uint4 kA[2], vA[2], rA[2], kB[2], vB[2], rB[2], rX[2];
    // prologue: tile 0 needs K(0), VT(0), R blocks (7-it) and (8-it)
    ldK(0, kA);
    ldV(0, vA);
    ldR((8 - it) * 64, rA);
    ldR((7 - it) * 64, rX);

    auto body = [&](int jt, uint4 (&kc)[2], uint4 (&vc)[2], uint4 (&rc)[2],
                    uint4 (&kn)[2], uint4 (&vn)[2], uint4 (&rn)[2]) {
        const int par = (jt - it) & 1;
        __syncthreads();
        // prefetch next tile first (counted vmcnt lets writes proceed)
        if (jt + 1 < ntiles) {
            ldK((jt + 1) * 64, kn);
            ldV((jt + 1) * 64, vn);
            ldR((9 + jt - it) * 64, rn);
        }
        st64(lK, kc);
        st64(lVT, vc);
        st64(lR[par], rc);
        if (jt == 0) st64(lR[par ^ 1], rX);
        __syncthreads();

        // ---- compute tile jt ----
        f32x4 sac[4] = {};
        f32x4 bd[5] = {};
#pragma unroll
        for (int kk = 0; kk < 2; ++kk) {
            const int cb = kk * 64 + lh * 16;
#pragma unroll
            for (int f = 0; f < 4; ++f) {
                bf16x8 kb = lds_read8_sw(lK, f * 16 + lane15, cb);
                sac[f] = __builtin_amdgcn_mfma_f32_16x16x32_bf16(qw[kk], kb, sac[f], 0, 0, 0);
            }
#pragma unroll
            for (int f = 0; f < 5; ++f) {
                int fa = fbase + f;
                int half = (par ^ 1) ^ (fa >> 2);
                bf16x8 rb = lds_read8_sw(lR[half], (fa & 3) * 16 + lane15, cb);
                bd[f] = __builtin_amdgcn_mfma_f32_16x16x32_bf16(qr[kk], rb, bd[f], 0, 0, 0);
            }
        }
        // park BD (f32) for diagonal-band gather
#pragma unroll
        for (int f = 0; f < 5; ++f)
#pragma unroll
            for (int r = 0; r < 4; ++r)
                lBD[w][(lh * 4 + r) * 83 + lane15 + 16 * f] = bd[f][r];

        float pv[4][4];
        float tmax[4] = {-1e30f, -1e30f, -1e30f, -1e30f};
        const bool lastTile = (jt == it + 8);
#pragma unroll
        for (int f = 0; f < 4; ++f) {
            int lj = lane15 + 16 * f;
#pragma unroll
            for (int r = 0; r < 4; ++r) {
                int cc = 15 + lj - lh * 4 - r;
                float s = (sac[f][r] + lBD[w][(lh * 4 + r) * 83 + cc]) * 0.125f;
                if (lastTile && (lj > rowl + r)) s = -1e30f;
                pv[f][r] = s;
                tmax[r] = fmaxf(tmax[r], s);
            }
        }
#pragma unroll
        for (int off = 1; off < 16; off <<= 1)
#pragma unroll
            for (int r = 0; r < 4; ++r)
                tmax[r] = fmaxf(tmax[r], __shfl_xor(tmax[r], off));

        float scal[4], tsum[4];
#pragma unroll
        for (int r = 0; r < 4; ++r) {
            float nm = fmaxf(mrow[r], tmax[r]);
            scal[r] = __expf(mrow[r] - nm);
            mrow[r] = nm;
            float ts = 0.f;
#pragma unroll
            for (int f = 0; f < 4; ++f) {
                float e = __expf(pv[f][r] - nm);
                pv[f][r] = e;
                ts += e;
            }
            tsum[r] = ts;
        }
#pragma unroll
        for (int off = 1; off < 16; off <<= 1)
#pragma unroll
            for (int r = 0; r < 4; ++r)
                tsum[r] += __shfl_xor(tsum[r], off);
#pragma unroll
        for (int r = 0; r < 4; ++r) {
            srow[r] = srow[r] * scal[r] + tsum[r];
#pragma unroll
            for (int f = 0; f < 4; ++f) oacc[f][r] *= scal[r];
        }
        // P -> bf16 LDS (swizzled), reload as A-fragments
#pragma unroll
        for (int f = 0; f < 4; ++f)
#pragma unroll
            for (int r = 0; r < 4; ++r) {
                int row = lh * 4 + r, cb2 = (lane15 + 16 * f) * 2;
                *(unsigned short*)((char*)lP[w] + row * 128 + (cb2 ^ ((row & 7) << 4))) =
                    f2bf(pv[f][r]);
            }
#pragma unroll
        for (int kk = 0; kk < 2; ++kk) {
            const int cb = kk * 64 + lh * 16;
            bf16x8 pa = lds_read8_sw(lP[w], lane15, cb);
#pragma unroll
            for (int f = 0; f < 4; ++f) {
                bf16x8 vb = lds_read8_sw(lVT, f * 16 + lane15, cb);
                oacc[f] = __builtin_amdgcn_mfma_f32_16x16x32_bf16(pa, vb, oacc[f], 0, 0, 0);
            }
        }
    };

    for (int jt = 0; jt < ntiles; ++jt) {
        if (jt & 1) body(jt, kB, vB, rB, kA, vA, rA);
        else        body(jt, kA, vA, rA, kB, vB, rB);
    }

    // write attn_vec [t][n*64+d] bf16, t = i*4 + b
#pragma unroll
    for (int r = 0; r < 4; ++r) {
        float inv = 1.0f / srow[r];
#pragma unroll
        for (int f = 0; f < 4; ++f) {
            int i = i0 + rowl + r;
            int t = i * 4 + b;
            int col = n * 64 + lane15 + 16 * f;
            avec[(size_t)t * DM + col] = f2bf(oacc[f][r] * inv);
        }
    }
}

// ---------------------------------------------------------------------------
// LayerNorm: h = LN(hin + res) * g + b ; emits f32 h and bf16 h
// ---------------------------------------------------------------------------
__global__ __launch_bounds__(256)
void ln_kernel(const float* __restrict__ hin, const float* __restrict__ res,
               const float* __restrict__ g, const float* __restrict__ bb,
               float* __restrict__ hout, unsigned short* __restrict__ hbf) {
    __shared__ float ls[8];
    const int t = blockIdx.x, tid = threadIdx.x;
    float4 x = ((const float4*)(hin + (size_t)t * DM))[tid];
    float4 rr = ((const float4*)(res + (size_t)t * DM))[tid];
    float v0 = x.x + rr.x, v1 = x.y + rr.y, v2 = x.z + rr.z, v3 = x.w + rr.w;
    float s = v0 + v1 + v2 + v3;
    float sq = v0 * v0 + v1 * v1 + v2 * v2 + v3 * v3;
#pragma unroll
    for (int off = 1; off < 64; off <<= 1) {
        s += __shfl_xor(s, off);
        sq += __shfl_xor(sq, off);
    }
    const int w = tid >> 6;
    if ((tid & 63) == 0) { ls[w] = s; ls[4 + w] = sq; }
    __syncthreads();
    s = ls[0] + ls[1] + ls[2] + ls[3];
    sq = ls[4] + ls[5] + ls[6] + ls[7];
    float mu = s * (1.f / 1024.f);
    float var = sq * (1.f / 1024.f) - mu * mu;
    float rstd = rsqrtf(var + 1e-5f);
    float y[4] = {v0, v1, v2, v3};
    float4 of;
    uint2 ob;
    float* op = &of.x;
#pragma unroll
    for (int j = 0; j < 4; ++j) {
        int d = tid * 4 + j;
        op[j] = (y[j] - mu) * rstd * g[d] + bb[d];
    }
    ob.x = (unsigned)f2bf(of.x) | ((unsigned)f2bf(of.y) << 16);
    ob.y = (unsigned)f2bf(of.z) | ((unsigned)f2bf(of.w) << 16);
    ((float4*)(hout + (size_t)t * DM))[tid] = of;
    ((uint2*)(hbf + (size_t)t * DM))[tid] = ob;
}

__global__ __launch_bounds__(256)
void out_kernel(const float* __restrict__ h, float* __restrict__ out) {
    const int t = blockIdx.x, tid = threadIdx.x;
    const int i = t >> 2, b = t & 3;
    ((float4*)(out + ((size_t)b * QLEN + i) * DM))[tid] =
        ((const float4*)(h + (size_t)t * DM))[tid];
}

// ---------------------------------------------------------------------------
extern "C" void kernel_launch(void* const* d_in, const int* in_sizes, int n_in,
                              void* d_out, int out_size, void* d_ws, size_t ws_size,
                              hipStream_t stream) {
    const int* ids = (const int*)d_in[0];
    const float* mems = (const float*)d_in[1];
    const float* embp[4] = {nullptr, nullptr, nullptr, nullptr};
    const float* projp[4] = {nullptr, nullptr, nullptr, nullptr};
    const long long esz[4] = {20000LL * 1024, 20000LL * 256, 160000LL * 64, 67735LL * 16};
    const long long psz[4] = {1024LL * 1024, 256LL * 1024, 64LL * 1024, 16LL * 1024};
    for (int idx = 2; idx <= 9 && idx < n_in; ++idx) {
        long long s = in_sizes[idx];
        for (int c = 0; c < 4; ++c) {
            if (s == esz[c]) embp[c] = (const float*)d_in[idx];
            else if (s == psz[c]) projp[c] = (const float*)d_in[idx];
        }
    }
    const float* qkvW = (const float*)d_in[10];
    const float* rW   = (const float*)d_in[11];
    const float* oW   = (const float*)d_in[12];
    const float* rwb  = (const float*)d_in[13];
    const float* rrb  = (const float*)d_in[14];
    const float* ln1g = (const float*)d_in[15];
    const float* ln1b = (const float*)d_in[16];
    const float* ffw1 = (const float*)d_in[17];
    const float* ffb1 = (const float*)d_in[18];
    const float* ffw2 = (const float*)d_in[19];
    const float* ffb2 = (const float*)d_in[20];
    const float* ln2g = (const float*)d_in[21];
    const float* ln2b = (const float*)d_in[22];

    size_t off = 0;
    char* base = (char*)d_ws;
    auto alloc = [&](size_t bytes) -> char* {
        char* p = base + off;
        off = (off + bytes + 255) & ~(size_t)255;
        return p;
    };
    unsigned short* qkvT  = (unsigned short*)alloc(3072ull * 1024 * 2);
    unsigned short* rT    = (unsigned short*)alloc(1024ull * 1024 * 2);
    unsigned short* oT    = (unsigned short*)alloc(1024ull * 1024 * 2);
    unsigned short* w1T   = (unsigned short*)alloc(4096ull * 1024 * 2);
    unsigned short* w2T   = (unsigned short*)alloc(1024ull * 4096 * 2);
    unsigned short* embA  = (unsigned short*)alloc(2048ull * EK * 2);
    unsigned short* embBT = (unsigned short*)alloc(1024ull * EK * 2);
    float* h              = (float*)alloc(2048ull * 1024 * 4);
    unsigned short* hbf   = (unsigned short*)alloc(2048ull * 1024 * 2);
    unsigned short* catb  = (unsigned short*)alloc(4096ull * 1024 * 2);
    unsigned short* posb  = (unsigned short*)alloc(1024ull * 1024 * 2);
    unsigned short* Qw    = (unsigned short*)alloc(4ull * 16 * 512 * 64 * 2);
    unsigned short* Qr    = (unsigned short*)alloc(4ull * 16 * 512 * 64 * 2);
    unsigned short* Kb    = (unsigned short*)alloc(4ull * 16 * 1024 * 64 * 2);
    unsigned short* VTb   = (unsigned short*)alloc(4ull * 16 * 1024 * 64 * 2);
    unsigned short* Rb    = (unsigned short*)alloc(16ull * 1024 * 64 * 2);
    unsigned short* avec  = (unsigned short*)alloc(2048ull * 1024 * 2);
    float* resid          = (float*)alloc(2048ull * 1024 * 4);
    unsigned short* ff1b  = (unsigned short*)alloc(2048ull * 4096 * 2);
    (void)ws_size; (void)out_size;

    // ---- embeddings (gather + GEMM) + positional table ----
    emb_gather<<<(2048 * 176 + 255) / 256, 256, 0, stream>>>(
        ids, embp[0], embp[1], embp[2], embp[3], embA);
    transpose_pad<<<dim3(32, 32), 256, 0, stream>>>(projp[0], embBT, 1024, 1024, EK, 0);
    transpose_pad<<<dim3(32, 8),  256, 0, stream>>>(projp[1], embBT, 256,  1024, EK, 1024);
    transpose_pad<<<dim3(32, 2),  256, 0, stream>>>(projp[2], embBT, 64,   1024, EK, 1280);
    transpose_pad<<<dim3(32, 2),  256, 0, stream>>>(projp[3], embBT, 16,   1024, EK, 1344);
    pos_kernel<<<1024, 256, 0, stream>>>(posb);
    gemm_bt<0><<<dim3(1024 / 128, 2048 / 128), 256, 0, stream>>>(
        embA, embBT, h, nullptr, nullptr, nullptr, nullptr, nullptr, nullptr, nullptr, nullptr,
        2048, 1024, EK);

    for (int l = 0; l < N_LAYER; ++l) {
        const float* qkvWl = qkvW + (size_t)l * 1024 * 3072;
        const float* rWl   = rW + (size_t)l * 1024 * 1024;
        const float* oWl   = oW + (size_t)l * 1024 * 1024;
        const float* w1l   = ffw1 + (size_t)l * 1024 * 4096;
        const float* w2l   = ffw2 + (size_t)l * 4096 * 1024;

        transpose_w<<<dim3(3072 / 32, 1024 / 32), 256, 0, stream>>>(qkvWl, qkvT, 1024, 3072);
        transpose_w<<<dim3(1024 / 32, 1024 / 32), 256, 0, stream>>>(rWl, rT, 1024, 1024);
        transpose_w<<<dim3(1024 / 32, 1024 / 32), 256, 0, stream>>>(oWl, oT, 1024, 1024);
        transpose_w<<<dim3(4096 / 32, 1024 / 32), 256, 0, stream>>>(w1l, w1T, 1024, 4096);
        transpose_w<<<dim3(1024 / 32, 4096 / 32), 256, 0, stream>>>(w2l, w2T, 4096, 1024);

        cat_kernel<<<4096, 256, 0, stream>>>(mems + (size_t)l * 2048 * 1024, h, catb);

        gemm_bt<3><<<dim3(3072 / 128, 4096 / 128), 256, 0, stream>>>(
            catb, qkvT, nullptr, nullptr, nullptr,
            rwb + l * 1024, rrb + l * 1024, Qw, Qr, Kb, VTb, 4096, 3072, 1024);

        gemm_bt<4><<<dim3(1024 / 128, 1024 / 128), 256, 0, stream>>>(
            posb, rT, nullptr, nullptr, nullptr,
            nullptr, nullptr, nullptr, nullptr, Rb, nullptr, 1024, 1024, 1024);

        attn_kernel<<<512, 256, 0, stream>>>(Qw, Qr, Kb, VTb, Rb, avec);

        gemm_bt<0><<<dim3(1024 / 128, 2048 / 128), 256, 0, stream>>>(
            avec, oT, resid, nullptr, nullptr, nullptr, nullptr, nullptr, nullptr, nullptr, nullptr,
            2048, 1024, 1024);
        ln_kernel<<<2048, 256, 0, stream>>>(h, resid, ln1g + l * 1024, ln1b + l * 1024, h, hbf);

        gemm_bt<1><<<dim3(4096 / 128, 2048 / 128), 256, 0, stream>>>(
            hbf, w1T, nullptr, ff1b, ffb1 + l * 4096, nullptr, nullptr, nullptr, nullptr, nullptr, nullptr,
            2048, 4096, 1024);
        gemm_bt<2><<<dim3(1024 / 128, 2048 / 128), 256, 0, stream>>>(
            ff1b, w2T, resid, nullptr, ffb2 + l * 1024, nullptr, nullptr, nullptr, nullptr, nullptr, nullptr,
            2048, 1024, 4096);
        ln_kernel<<<2048, 256, 0, stream>>>(h, resid, ln2g + l * 1024, ln2b + l * 1024, h, hbf);
    }

    out_kernel<<<2048, 256, 0, stream>>>(h, (float*)d_out);
}

// Round 4
// 1275.120 us; speedup vs baseline: 2.2648x; 1.0554x over previous
//
#include <hip/hip_runtime.h>

typedef __attribute__((ext_vector_type(8))) short bf16x8;
typedef __attribute__((ext_vector_type(4))) float f32x4;

#define N_LAYER 4
#define QLEN 512
#define MLEN 512
#define KLEN 1024
#define BSZ 4
#define DM 1024
#define NH 16
#define DH 64
#define DINNER 4096
#define EK 1408  // padded adaptive-emb K: 1024 + 256 + 64 + 64(pad from 16)

__device__ __forceinline__ unsigned short f2bf(float x) {
    unsigned u = __float_as_uint(x);
    u += 0x7fffu + ((u >> 16) & 1u);
    return (unsigned short)(u >> 16);
}
__device__ __forceinline__ float bf2f(unsigned short v) {
    return __uint_as_float(((unsigned)v) << 16);
}

__device__ __forceinline__ void gload16(const unsigned short* g, unsigned short* l) {
    __builtin_amdgcn_global_load_lds(
        (const __attribute__((address_space(1))) unsigned int*)g,
        (__attribute__((address_space(3))) unsigned int*)l, 16, 0, 0);
}

// swizzled b128 LDS read for 128B-row-stride bf16 tiles: byte ^= (row&7)<<4
__device__ __forceinline__ bf16x8 lds_read8_sw(const unsigned short* base, int row, int cb) {
    return *(const bf16x8*)((const char*)base + row * 128 + (cb ^ ((row & 7) << 4)));
}

// ---------------------------------------------------------------------------
// Weight transpose + f32->bf16:  W (K x N) -> WT (N x K) bf16
// ---------------------------------------------------------------------------
__global__ __launch_bounds__(256)
void transpose_w(const float* __restrict__ W, unsigned short* __restrict__ WT,
                 int K, int N) {
    __shared__ float tile[32][33];
    const int tx = threadIdx.x & 31, ty = threadIdx.x >> 5;
    const int bx = blockIdx.x, by = blockIdx.y;
#pragma unroll
    for (int i = 0; i < 4; ++i)
        tile[ty + i * 8][tx] = W[(size_t)(by * 32 + ty + i * 8) * N + bx * 32 + tx];
    __syncthreads();
#pragma unroll
    for (int i = 0; i < 4; ++i)
        WT[(size_t)(bx * 32 + ty + i * 8) * K + by * 32 + tx] = f2bf(tile[tx][ty + i * 8]);
}

// Transpose with zero-padding beyond K rows, into a slice of a wider dst row.
__global__ __launch_bounds__(256)
void transpose_pad(const float* __restrict__ W, unsigned short* __restrict__ dst,
                   int K, int N, int dstLD, int dstOff) {
    __shared__ float tile[32][33];
    const int tx = threadIdx.x & 31, ty = threadIdx.x >> 5;
    const int bx = blockIdx.x, by = blockIdx.y;
#pragma unroll
    for (int i = 0; i < 4; ++i) {
        int k = by * 32 + ty + i * 8;
        tile[ty + i * 8][tx] = (k < K) ? W[(size_t)k * N + bx * 32 + tx] : 0.f;
    }
    __syncthreads();
#pragma unroll
    for (int i = 0; i < 4; ++i) {
        int n = bx * 32 + ty + i * 8;
        int k = by * 32 + tx;
        dst[(size_t)n * dstLD + dstOff + k] = f2bf(tile[tx][ty + i * 8]);
    }
}

// ---------------------------------------------------------------------------
// Adaptive-embedding gather: embA[t][0:1408) = masked cluster row * 32, bf16
// ---------------------------------------------------------------------------
__global__ __launch_bounds__(256)
void emb_gather(const int* __restrict__ ids,
                const float* __restrict__ e0, const float* __restrict__ e1,
                const float* __restrict__ e2, const float* __restrict__ e3,
                unsigned short* __restrict__ embA) {
    const int chunk = blockIdx.x * 256 + threadIdx.x;
    if (chunk >= 2048 * 176) return;
    const int t = chunk / 176;
    const int e8 = (chunk - t * 176) * 8;
    const int i = t >> 2, b = t & 3;
    const int id = ids[b * QLEN + i];
    const float* src = nullptr;
    if (e8 < 1024) {
        if (id < 20000) src = e0 + (size_t)id * 1024 + e8;
    } else if (e8 < 1280) {
        if (id >= 20000 && id < 40000) src = e1 + (size_t)(id - 20000) * 256 + (e8 - 1024);
    } else if (e8 < 1344) {
        if (id >= 40000 && id < 200000) src = e2 + (size_t)(id - 40000) * 64 + (e8 - 1280);
    } else if (e8 < 1360) {
        if (id >= 200000) src = e3 + (size_t)(id - 200000) * 16 + (e8 - 1344);
    }
    uint4 o = {0u, 0u, 0u, 0u};
    if (src) {
        float4 v0 = *(const float4*)src;
        float4 v1 = *(const float4*)(src + 4);
        o.x = (unsigned)f2bf(v0.x * 32.f) | ((unsigned)f2bf(v0.y * 32.f) << 16);
        o.y = (unsigned)f2bf(v0.z * 32.f) | ((unsigned)f2bf(v0.w * 32.f) << 16);
        o.z = (unsigned)f2bf(v1.x * 32.f) | ((unsigned)f2bf(v1.y * 32.f) << 16);
        o.w = (unsigned)f2bf(v1.z * 32.f) | ((unsigned)f2bf(v1.w * 32.f) << 16);
    }
    *(uint4*)(embA + (size_t)t * EK + e8) = o;
}

// ---------------------------------------------------------------------------
// GEMM: C[M,N] = A[M,K] @ B[K,N], A bf16 row-major, BT = B^T bf16 (N x K)
// T3 minimum-2-phase: double-buffered global_load_lds, STAGE(next) issued
// BEFORE compute(cur), single barrier per K-step. T2 via pre-swizzled source.
// ---------------------------------------------------------------------------
template <int MODE>
__global__ __launch_bounds__(256)
void gemm_bt(const unsigned short* __restrict__ A, const unsigned short* __restrict__ BT,
             float* __restrict__ C, unsigned short* __restrict__ Cbf,
             const float* __restrict__ bias,
             const float* __restrict__ rwb, const float* __restrict__ rrb,
             unsigned short* __restrict__ Qw, unsigned short* __restrict__ Qr,
             unsigned short* __restrict__ Kb, unsigned short* __restrict__ VTb,
             int M, int N, int K) {
    __shared__ unsigned short lA[2][128 * 64];
    __shared__ unsigned short lB[2][128 * 64];
    const int tid = threadIdx.x;
    const int w = tid >> 6, l = tid & 63;
    const int lane15 = l & 15, lh = l >> 4;
    const int bm = blockIdx.y, bn = blockIdx.x;
    const int wr = (w >> 1) * 64, wc = (w & 1) * 64;

    f32x4 acc[4][4] = {};

    const int srow = tid >> 3;                       // 0..31
    const int scol = ((tid & 7) ^ (srow & 7)) * 8;   // inverse-swizzled source col
    const unsigned short* gA = A + (size_t)(bm * 128 + srow) * K + scol;
    const unsigned short* gB = BT + (size_t)(bn * 128 + srow) * K + scol;

    auto stage = [&](int buf, int k0) {
#pragma unroll
        for (int it = 0; it < 4; ++it) {
            gload16(gA + (size_t)(it * 32) * K + k0, lA[buf] + tid * 8 + it * 2048);
            gload16(gB + (size_t)(it * 32) * K + k0, lB[buf] + tid * 8 + it * 2048);
        }
    };

    stage(0, 0);
    __syncthreads();   // implicit vmcnt(0) drain before first compute
    int cur = 0;
    for (int k0 = 0; k0 < K; k0 += 64) {
        if (k0 + 64 < K) stage(cur ^ 1, k0 + 64);   // overlap with compute below
        const unsigned short* cA = lA[cur];
        const unsigned short* cB = lB[cur];
#pragma unroll
        for (int kk = 0; kk < 2; ++kk) {
            bf16x8 af[4], bfr[4];
#pragma unroll
            for (int f = 0; f < 4; ++f) {
                af[f]  = lds_read8_sw(cA, wr + f * 16 + lane15, kk * 64 + lh * 16);
                bfr[f] = lds_read8_sw(cB, wc + f * 16 + lane15, kk * 64 + lh * 16);
            }
#pragma unroll
            for (int mi = 0; mi < 4; ++mi)
#pragma unroll
                for (int ni = 0; ni < 4; ++ni)
                    acc[mi][ni] = __builtin_amdgcn_mfma_f32_16x16x32_bf16(
                        af[mi], bfr[ni], acc[mi][ni], 0, 0, 0);
        }
        __syncthreads();   // drains prefetch loads; orders buffer reuse
        cur ^= 1;
    }

#pragma unroll
    for (int mi = 0; mi < 4; ++mi) {
        int rowb = bm * 128 + wr + mi * 16 + lh * 4;   // multiple of 4
#pragma unroll
        for (int ni = 0; ni < 4; ++ni) {
            int col = bn * 128 + wc + ni * 16 + lane15;
#pragma unroll
            for (int r = 0; r < 4; ++r) {
                float x = acc[mi][ni][r];
                if (MODE == 0) {
                    C[(size_t)(rowb + r) * N + col] = x;
                } else if (MODE == 1) {
                    x += bias[col];
                    Cbf[(size_t)(rowb + r) * N + col] = f2bf(x > 0.f ? x : 0.f);
                } else if (MODE == 2) {
                    C[(size_t)(rowb + r) * N + col] = x + bias[col];
                } else if (MODE == 3) {
                    int j = rowb >> 2;
                    int bb_ = r;
                    if (col < 1024) {
                        if (j >= MLEN) {
                            int i = j - MLEN, n = col >> 6, d = col & 63;
                            size_t o = ((size_t)(bb_ * NH + n) * QLEN + i) * DH + d;
                            Qw[o] = f2bf(x + rwb[col]);
                            Qr[o] = f2bf(x + rrb[col]);
                        }
                    } else if (col < 2048) {
                        int c2 = col - 1024, n = c2 >> 6, d = c2 & 63;
                        Kb[((size_t)(bb_ * NH + n) * KLEN + j) * DH + d] = f2bf(x);
                    } else {
                        int c2 = col - 2048, n = c2 >> 6, d = c2 & 63;
                        VTb[((size_t)(bb_ * NH + n) * DH + d) * KLEN + j] = f2bf(x);
                    }
                } else { // MODE 4
                    int j = rowb + r;
                    int n = col >> 6, d = col & 63;
                    Kb[((size_t)n * KLEN + j) * DH + d] = f2bf(x);  // Kb := Rb here
                }
            }
        }
    }
}

// ---------------------------------------------------------------------------
// Positional embedding table (1024 x 1024), bf16
// ---------------------------------------------------------------------------
__global__ __launch_bounds__(256)
void pos_kernel(unsigned short* __restrict__ posbf) {
    const int p = blockIdx.x, tid = threadIdx.x;
    const float ps = (float)(KLEN - 1 - p);
    const float c = -2.0f * 9.210340371976184f / 1024.0f; // -2*ln(10000)/D
#pragma unroll
    for (int j4 = 0; j4 < 4; ++j4) {
        int j = tid + j4 * 256;
        int m = (j < 512) ? j : j - 512;
        float freq = __expf((float)m * c);
        float ang = ps * freq;
        float v = (j < 512) ? sinf(ang) : cosf(ang);
        posbf[(size_t)p * DM + j] = f2bf(v);
    }
}

// ---------------------------------------------------------------------------
// cat = [mems_l ; h] -> bf16 (4096 x 1024)
// ---------------------------------------------------------------------------
__global__ __launch_bounds__(256)
void cat_kernel(const float* __restrict__ mem_l, const float* __restrict__ h,
                unsigned short* __restrict__ catbf) {
    const int t = blockIdx.x, tid = threadIdx.x;
    const float* src = (t < 2048) ? (mem_l + (size_t)t * DM) : (h + (size_t)(t - 2048) * DM);
    float4 v = ((const float4*)src)[tid];
    uint2 o;
    o.x = (unsigned)f2bf(v.x) | ((unsigned)f2bf(v.y) << 16);
    o.y = (unsigned)f2bf(v.z) | ((unsigned)f2bf(v.w) << 16);
    ((uint2*)(catbf + (size_t)t * DM))[tid] = o;
}

// ---------------------------------------------------------------------------
// Fused rel-attention. Block = (b, n, 64-row i-tile), 4 independent waves.
// NO staging, NO barriers: K/V/R fragments read directly from global
// (L2-resident via XCD-local decode). Per-wave LDS only for BD gather + P.
// T13 defer-max, T5 setprio around MFMA clusters.
// ---------------------------------------------------------------------------
__global__ __launch_bounds__(256)
void attn_kernel(const unsigned short* __restrict__ Qw, const unsigned short* __restrict__ Qr,
                 const unsigned short* __restrict__ Kb, const unsigned short* __restrict__ VTb,
                 const unsigned short* __restrict__ Rb, unsigned short* __restrict__ avec) {
    __shared__ float lBD[4][16 * 83];           // per-wave BD band, stride 83
    __shared__ unsigned short lP[4][16 * 64];   // per-wave P roundtrip (swizzled)

    const int tid = threadIdx.x;
    const int w = tid >> 6, l = tid & 63;
    const int lane15 = l & 15, lh = l >> 4;
    const int blk = blockIdx.x;
    const int bn = blk & 63;          // blk%8 == bn%8 -> all it of one head on one XCD
    const int it = blk >> 6;
    const int n = bn & 15, b = bn >> 4;
    const int i0 = it * 64;
    const int rowl = w * 16 + lh * 4;

    // Q fragments (resident)
    bf16x8 qw[2], qr[2];
    {
        size_t qb = ((size_t)bn * QLEN + i0 + w * 16 + lane15) * DH + lh * 8;
        qw[0] = *(const bf16x8*)(Qw + qb);
        qw[1] = *(const bf16x8*)(Qw + qb + 32);
        qr[0] = *(const bf16x8*)(Qr + qb);
        qr[1] = *(const bf16x8*)(Qr + qb + 32);
    }

    const unsigned short* Kh = Kb + (size_t)bn * KLEN * DH;
    const unsigned short* Vh = VTb + (size_t)bn * DH * KLEN;
    const unsigned short* Rh = Rb + (size_t)n * KLEN * DH;

    f32x4 oacc[4] = {};
    float mrow[4], srow[4];
#pragma unroll
    for (int r = 0; r < 4; ++r) { mrow[r] = -1e30f; srow[r] = 0.f; }

    const int ntiles = it + 9;
    for (int jt = 0; jt < ntiles; ++jt) {
        const int j0 = jt * 64;
        // ---- load K (8) and R (10) fragments directly from global ----
        bf16x8 kf[2][4], rf[2][5];
#pragma unroll
        for (int f = 0; f < 4; ++f) {
            const unsigned short* p = Kh + (size_t)(j0 + f * 16 + lane15) * DH + lh * 8;
            kf[0][f] = *(const bf16x8*)p;
            kf[1][f] = *(const bf16x8*)(p + 32);
        }
#pragma unroll
        for (int f = 0; f < 5; ++f) {
            int rr = 496 + 64 * (jt - it) - 16 * w + 16 * f + lane15;
            if (rr > 1023) rr = 1023;   // clamped rows are always masked
            const unsigned short* p = Rh + (size_t)rr * DH + lh * 8;
            rf[0][f] = *(const bf16x8*)p;
            rf[1][f] = *(const bf16x8*)(p + 32);
        }

        f32x4 sac[4] = {};
        f32x4 bd[5] = {};
        __builtin_amdgcn_s_setprio(1);
#pragma unroll
        for (int kk = 0; kk < 2; ++kk) {
#pragma unroll
            for (int f = 0; f < 4; ++f)
                sac[f] = __builtin_amdgcn_mfma_f32_16x16x32_bf16(qw[kk], kf[kk][f], sac[f], 0, 0, 0);
#pragma unroll
            for (int f = 0; f < 5; ++f)
                bd[f] = __builtin_amdgcn_mfma_f32_16x16x32_bf16(qr[kk], rf[kk][f], bd[f], 0, 0, 0);
        }
        __builtin_amdgcn_s_setprio(0);

        // park BD (f32) for the diagonal-band gather (per-wave region)
#pragma unroll
        for (int f = 0; f < 5; ++f)
#pragma unroll
            for (int r = 0; r < 4; ++r)
                lBD[w][(lh * 4 + r) * 83 + lane15 + 16 * f] = bd[f][r];

        float pv[4][4];
        float tmax[4] = {-1e30f, -1e30f, -1e30f, -1e30f};
        const bool lastTile = (jt == it + 8);
#pragma unroll
        for (int f = 0; f < 4; ++f) {
            int lj = lane15 + 16 * f;
#pragma unroll
            for (int r = 0; r < 4; ++r) {
                int cc = 15 + lj - lh * 4 - r;
                float s = (sac[f][r] + lBD[w][(lh * 4 + r) * 83 + cc]) * 0.125f;
                if (lastTile && (lj > rowl + r)) s = -1e30f;
                pv[f][r] = s;
                tmax[r] = fmaxf(tmax[r], s);
            }
        }
#pragma unroll
        for (int off = 1; off < 16; off <<= 1)
#pragma unroll
            for (int r = 0; r < 4; ++r)
                tmax[r] = fmaxf(tmax[r], __shfl_xor(tmax[r], off));

        // T13 defer-max: skip rescale while per-tile max growth <= 8
        bool grow = false;
#pragma unroll
        for (int r = 0; r < 4; ++r) grow = grow || (tmax[r] > mrow[r] + 8.f);
        if (__any(grow)) {
#pragma unroll
            for (int r = 0; r < 4; ++r) {
                float nm = fmaxf(mrow[r], tmax[r]);
                float sc = __expf(mrow[r] - nm);
                mrow[r] = nm;
                srow[r] *= sc;
#pragma unroll
                for (int f = 0; f < 4; ++f) oacc[f][r] *= sc;
            }
        }
        float tsum[4];
#pragma unroll
        for (int r = 0; r < 4; ++r) {
            float ts = 0.f;
#pragma unroll
            for (int f = 0; f < 4; ++f) {
                float e = __expf(pv[f][r] - mrow[r]);
                pv[f][r] = e;
                ts += e;
            }
            tsum[r] = ts;
        }
#pragma unroll
        for (int off = 1; off < 16; off <<= 1)
#pragma unroll
            for (int r = 0; r < 4; ++r)
                tsum[r] += __shfl_xor(tsum[r], off);
#pragma unroll
        for (int r = 0; r < 4; ++r) srow[r] += tsum[r];

        // P -> bf16 LDS (swizzled, per-wave), reload as A-fragments
#pragma unroll
        for (int f = 0; f < 4; ++f)
#pragma unroll
            for (int r = 0; r < 4; ++r) {
                int row = lh * 4 + r, cb2 = (lane15 + 16 * f) * 2;
                *(unsigned short*)((char*)lP[w] + row * 128 + (cb2 ^ ((row & 7) << 4))) =
                    f2bf(pv[f][r]);
            }
        bf16x8 pa[2];
        pa[0] = lds_read8_sw(lP[w], lane15, lh * 16);
        pa[1] = lds_read8_sw(lP[w], lane15, 64 + lh * 16);

        __builtin_amdgcn_s_setprio(1);
#pragma unroll
        for (int kk = 0; kk < 2; ++kk) {
#pragma unroll
            for (int f = 0; f < 4; ++f) {
                bf16x8 vb = *(const bf16x8*)(Vh + (size_t)(f * 16 + lane15) * KLEN + j0 + kk * 32 + lh * 8);
                oacc[f] = __builtin_amdgcn_mfma_f32_16x16x32_bf16(pa[kk], vb, oacc[f], 0, 0, 0);
            }
        }
        __builtin_amdgcn_s_setprio(0);
    }

    // write attn_vec [t][n*64+d] bf16, t = i*4 + b
#pragma unroll
    for (int r = 0; r < 4; ++r) {
        float inv = 1.0f / srow[r];
#pragma unroll
        for (int f = 0; f < 4; ++f) {
            int i = i0 + rowl + r;
            int t = i * 4 + b;
            int col = n * 64 + lane15 + 16 * f;
            avec[(size_t)t * DM + col] = f2bf(oacc[f][r] * inv);
        }
    }
}

// ---------------------------------------------------------------------------
// LayerNorm: h = LN(hin + res) * g + b ; emits f32 h and bf16 h
// ---------------------------------------------------------------------------
__global__ __launch_bounds__(256)
void ln_kernel(const float* __restrict__ hin, const float* __restrict__ res,
               const float* __restrict__ g, const float* __restrict__ bb,
               float* __restrict__ hout, unsigned short* __restrict__ hbf) {
    __shared__ float ls[8];
    const int t = blockIdx.x, tid = threadIdx.x;
    float4 x = ((const float4*)(hin + (size_t)t * DM))[tid];
    float4 rr = ((const float4*)(res + (size_t)t * DM))[tid];
    float v0 = x.x + rr.x, v1 = x.y + rr.y, v2 = x.z + rr.z, v3 = x.w + rr.w;
    float s = v0 + v1 + v2 + v3;
    float sq = v0 * v0 + v1 * v1 + v2 * v2 + v3 * v3;
#pragma unroll
    for (int off = 1; off < 64; off <<= 1) {
        s += __shfl_xor(s, off);
        sq += __shfl_xor(sq, off);
    }
    const int w = tid >> 6;
    if ((tid & 63) == 0) { ls[w] = s; ls[4 + w] = sq; }
    __syncthreads();
    s = ls[0] + ls[1] + ls[2] + ls[3];
    sq = ls[4] + ls[5] + ls[6] + ls[7];
    float mu = s * (1.f / 1024.f);
    float var = sq * (1.f / 1024.f) - mu * mu;
    float rstd = rsqrtf(var + 1e-5f);
    float y[4] = {v0, v1, v2, v3};
    float4 of;
    uint2 ob;
    float* op = &of.x;
#pragma unroll
    for (int j = 0; j < 4; ++j) {
        int d = tid * 4 + j;
        op[j] = (y[j] - mu) * rstd * g[d] + bb[d];
    }
    ob.x = (unsigned)f2bf(of.x) | ((unsigned)f2bf(of.y) << 16);
    ob.y = (unsigned)f2bf(of.z) | ((unsigned)f2bf(of.w) << 16);
    ((float4*)(hout + (size_t)t * DM))[tid] = of;
    ((uint2*)(hbf + (size_t)t * DM))[tid] = ob;
}

__global__ __launch_bounds__(256)
void out_kernel(const float* __restrict__ h, float* __restrict__ out) {
    const int t = blockIdx.x, tid = threadIdx.x;
    const int i = t >> 2, b = t & 3;
    ((float4*)(out + ((size_t)b * QLEN + i) * DM))[tid] =
        ((const float4*)(h + (size_t)t * DM))[tid];
}

// ---------------------------------------------------------------------------
extern "C" void kernel_launch(void* const* d_in, const int* in_sizes, int n_in,
                              void* d_out, int out_size, void* d_ws, size_t ws_size,
                              hipStream_t stream) {
    const int* ids = (const int*)d_in[0];
    const float* mems = (const float*)d_in[1];
    const float* embp[4] = {nullptr, nullptr, nullptr, nullptr};
    const float* projp[4] = {nullptr, nullptr, nullptr, nullptr};
    const long long esz[4] = {20000LL * 1024, 20000LL * 256, 160000LL * 64, 67735LL * 16};
    const long long psz[4] = {1024LL * 1024, 256LL * 1024, 64LL * 1024, 16LL * 1024};
    for (int idx = 2; idx <= 9 && idx < n_in; ++idx) {
        long long s = in_sizes[idx];
        for (int c = 0; c < 4; ++c) {
            if (s == esz[c]) embp[c] = (const float*)d_in[idx];
            else if (s == psz[c]) projp[c] = (const float*)d_in[idx];
        }
    }
    const float* qkvW = (const float*)d_in[10];
    const float* rW   = (const float*)d_in[11];
    const float* oW   = (const float*)d_in[12];
    const float* rwb  = (const float*)d_in[13];
    const float* rrb  = (const float*)d_in[14];
    const float* ln1g = (const float*)d_in[15];
    const float* ln1b = (const float*)d_in[16];
    const float* ffw1 = (const float*)d_in[17];
    const float* ffb1 = (const float*)d_in[18];
    const float* ffw2 = (const float*)d_in[19];
    const float* ffb2 = (const float*)d_in[20];
    const float* ln2g = (const float*)d_in[21];
    const float* ln2b = (const float*)d_in[22];

    size_t off = 0;
    char* base = (char*)d_ws;
    auto alloc = [&](size_t bytes) -> char* {
        char* p = base + off;
        off = (off + bytes + 255) & ~(size_t)255;
        return p;
    };
    unsigned short* qkvT  = (unsigned short*)alloc(3072ull * 1024 * 2);
    unsigned short* rT    = (unsigned short*)alloc(1024ull * 1024 * 2);
    unsigned short* oT    = (unsigned short*)alloc(1024ull * 1024 * 2);
    unsigned short* w1T   = (unsigned short*)alloc(4096ull * 1024 * 2);
    unsigned short* w2T   = (unsigned short*)alloc(1024ull * 4096 * 2);
    unsigned short* embA  = (unsigned short*)alloc(2048ull * EK * 2);
    unsigned short* embBT = (unsigned short*)alloc(1024ull * EK * 2);
    float* h              = (float*)alloc(2048ull * 1024 * 4);
    unsigned short* hbf   = (unsigned short*)alloc(2048ull * 1024 * 2);
    unsigned short* catb  = (unsigned short*)alloc(4096ull * 1024 * 2);
    unsigned short* posb  = (unsigned short*)alloc(1024ull * 1024 * 2);
    unsigned short* Qw    = (unsigned short*)alloc(4ull * 16 * 512 * 64 * 2);
    unsigned short* Qr    = (unsigned short*)alloc(4ull * 16 * 512 * 64 * 2);
    unsigned short* Kb    = (unsigned short*)alloc(4ull * 16 * 1024 * 64 * 2);
    unsigned short* VTb   = (unsigned short*)alloc(4ull * 16 * 1024 * 64 * 2);
    unsigned short* Rb    = (unsigned short*)alloc(16ull * 1024 * 64 * 2);
    unsigned short* avec  = (unsigned short*)alloc(2048ull * 1024 * 2);
    float* resid          = (float*)alloc(2048ull * 1024 * 4);
    unsigned short* ff1b  = (unsigned short*)alloc(2048ull * 4096 * 2);
    (void)ws_size; (void)out_size;

    // ---- embeddings (gather + GEMM) + positional table ----
    emb_gather<<<(2048 * 176 + 255) / 256, 256, 0, stream>>>(
        ids, embp[0], embp[1], embp[2], embp[3], embA);
    transpose_pad<<<dim3(32, 32), 256, 0, stream>>>(projp[0], embBT, 1024, 1024, EK, 0);
    transpose_pad<<<dim3(32, 8),  256, 0, stream>>>(projp[1], embBT, 256,  1024, EK, 1024);
    transpose_pad<<<dim3(32, 2),  256, 0, stream>>>(projp[2], embBT, 64,   1024, EK, 1280);
    transpose_pad<<<dim3(32, 2),  256, 0, stream>>>(projp[3], embBT, 16,   1024, EK, 1344);
    pos_kernel<<<1024, 256, 0, stream>>>(posb);
    gemm_bt<0><<<dim3(1024 / 128, 2048 / 128), 256, 0, stream>>>(
        embA, embBT, h, nullptr, nullptr, nullptr, nullptr, nullptr, nullptr, nullptr, nullptr,
        2048, 1024, EK);

    for (int l = 0; l < N_LAYER; ++l) {
        const float* qkvWl = qkvW + (size_t)l * 1024 * 3072;
        const float* rWl   = rW + (size_t)l * 1024 * 1024;
        const float* oWl   = oW + (size_t)l * 1024 * 1024;
        const float* w1l   = ffw1 + (size_t)l * 1024 * 4096;
        const float* w2l   = ffw2 + (size_t)l * 4096 * 1024;

        transpose_w<<<dim3(3072 / 32, 1024 / 32), 256, 0, stream>>>(qkvWl, qkvT, 1024, 3072);
        transpose_w<<<dim3(1024 / 32, 1024 / 32), 256, 0, stream>>>(rWl, rT, 1024, 1024);
        transpose_w<<<dim3(1024 / 32, 1024 / 32), 256, 0, stream>>>(oWl, oT, 1024, 1024);
        transpose_w<<<dim3(4096 / 32, 1024 / 32), 256, 0, stream>>>(w1l, w1T, 1024, 4096);
        transpose_w<<<dim3(1024 / 32, 4096 / 32), 256, 0, stream>>>(w2l, w2T, 4096, 1024);

        cat_kernel<<<4096, 256, 0, stream>>>(mems + (size_t)l * 2048 * 1024, h, catb);

        gemm_bt<3><<<dim3(3072 / 128, 4096 / 128), 256, 0, stream>>>(
            catb, qkvT, nullptr, nullptr, nullptr,
            rwb + l * 1024, rrb + l * 1024, Qw, Qr, Kb, VTb, 4096, 3072, 1024);

        gemm_bt<4><<<dim3(1024 / 128, 1024 / 128), 256, 0, stream>>>(
            posb, rT, nullptr, nullptr, nullptr,
            nullptr, nullptr, nullptr, nullptr, Rb, nullptr, 1024, 1024, 1024);

        attn_kernel<<<512, 256, 0, stream>>>(Qw, Qr, Kb, VTb, Rb, avec);

        gemm_bt<0><<<dim3(1024 / 128, 2048 / 128), 256, 0, stream>>>(
            avec, oT, resid, nullptr, nullptr, nullptr, nullptr, nullptr, nullptr, nullptr, nullptr,
            2048, 1024, 1024);
        ln_kernel<<<2048, 256, 0, stream>>>(h, resid, ln1g + l * 1024, ln1b + l * 1024, h, hbf);

        gemm_bt<1><<<dim3(4096 / 128, 2048 / 128), 256, 0, stream>>>(
            hbf, w1T, nullptr, ff1b, ffb1 + l * 4096, nullptr, nullptr, nullptr, nullptr, nullptr, nullptr,
            2048, 4096, 1024);
        gemm_bt<2><<<dim3(1024 / 128, 2048 / 128), 256, 0, stream>>>(
            ff1b, w2T, resid, nullptr, ffb2 + l * 1024, nullptr, nullptr, nullptr, nullptr, nullptr, nullptr,
            2048, 1024, 4096);
        ln_kernel<<<2048, 256, 0, stream>>>(h, resid, ln2g + l * 1024, ln2b + l * 1024, h, hbf);
    }

    out_kernel<<<2048, 256, 0, stream>>>(h, (float*)d_out);
}

// Round 5
// 1176.645 us; speedup vs baseline: 2.4544x; 1.0837x over previous
//
#include <hip/hip_runtime.h>

typedef __attribute__((ext_vector_type(8))) short bf16x8;
typedef __attribute__((ext_vector_type(4))) float f32x4;

#define N_LAYER 4
#define QLEN 512
#define MLEN 512
#define KLEN 1024
#define BSZ 4
#define DM 1024
#define NH 16
#define DH 64
#define DINNER 4096
#define EK 1408  // padded adaptive-emb K: 1024 + 256 + 64 + 64(pad from 16)

__device__ __forceinline__ unsigned short f2bf(float x) {
    unsigned u = __float_as_uint(x);
    u += 0x7fffu + ((u >> 16) & 1u);
    return (unsigned short)(u >> 16);
}
__device__ __forceinline__ float bf2f(unsigned short v) {
    return __uint_as_float(((unsigned)v) << 16);
}

__device__ __forceinline__ void gload16(const unsigned short* g, unsigned short* l) {
    __builtin_amdgcn_global_load_lds(
        (const __attribute__((address_space(1))) unsigned int*)g,
        (__attribute__((address_space(3))) unsigned int*)l, 16, 0, 0);
}

// swizzled b128 LDS read for 128B-row-stride bf16 tiles: byte ^= (row&7)<<4
__device__ __forceinline__ bf16x8 lds_read8_sw(const unsigned short* base, int row, int cb) {
    return *(const bf16x8*)((const char*)base + row * 128 + (cb ^ ((row & 7) << 4)));
}

// ---------------------------------------------------------------------------
// All 5 per-layer weight transposes in ONE launch (range-decoded blockIdx).
// W (K x N) f32 -> WT (N x K) bf16
// ---------------------------------------------------------------------------
__global__ __launch_bounds__(256)
void transpose_all(const float* __restrict__ qkvWl, const float* __restrict__ rWl,
                   const float* __restrict__ oWl, const float* __restrict__ w1l,
                   const float* __restrict__ w2l,
                   unsigned short* __restrict__ qkvT, unsigned short* __restrict__ rT,
                   unsigned short* __restrict__ oT, unsigned short* __restrict__ w1T,
                   unsigned short* __restrict__ w2T) {
    __shared__ float tile[32][33];
    int id = blockIdx.x;
    const float* W; unsigned short* D; int K, N, bx, by;
    if (id < 3072)      { W = qkvWl; D = qkvT; K = 1024; N = 3072; bx = id % 96;  by = id / 96; }
    else if (id < 4096) { id -= 3072; W = rWl;  D = rT;  K = 1024; N = 1024; bx = id & 31; by = id >> 5; }
    else if (id < 5120) { id -= 4096; W = oWl;  D = oT;  K = 1024; N = 1024; bx = id & 31; by = id >> 5; }
    else if (id < 9216) { id -= 5120; W = w1l;  D = w1T; K = 1024; N = 4096; bx = id & 127; by = id >> 7; }
    else                { id -= 9216; W = w2l;  D = w2T; K = 4096; N = 1024; bx = id & 31; by = id >> 5; }
    const int tx = threadIdx.x & 31, ty = threadIdx.x >> 5;
#pragma unroll
    for (int i = 0; i < 4; ++i)
        tile[ty + i * 8][tx] = W[(size_t)(by * 32 + ty + i * 8) * N + bx * 32 + tx];
    __syncthreads();
#pragma unroll
    for (int i = 0; i < 4; ++i)
        D[(size_t)(bx * 32 + ty + i * 8) * K + by * 32 + tx] = f2bf(tile[tx][ty + i * 8]);
}

// Transpose with zero-padding beyond K rows, into a slice of a wider dst row.
__global__ __launch_bounds__(256)
void transpose_pad(const float* __restrict__ W, unsigned short* __restrict__ dst,
                   int K, int N, int dstLD, int dstOff) {
    __shared__ float tile[32][33];
    const int tx = threadIdx.x & 31, ty = threadIdx.x >> 5;
    const int bx = blockIdx.x, by = blockIdx.y;
#pragma unroll
    for (int i = 0; i < 4; ++i) {
        int k = by * 32 + ty + i * 8;
        tile[ty + i * 8][tx] = (k < K) ? W[(size_t)k * N + bx * 32 + tx] : 0.f;
    }
    __syncthreads();
#pragma unroll
    for (int i = 0; i < 4; ++i) {
        int n = bx * 32 + ty + i * 8;
        int k = by * 32 + tx;
        dst[(size_t)n * dstLD + dstOff + k] = f2bf(tile[tx][ty + i * 8]);
    }
}

// ---------------------------------------------------------------------------
// Adaptive-embedding gather: embA[t][0:1408) = masked cluster row * 32, bf16
// ---------------------------------------------------------------------------
__global__ __launch_bounds__(256)
void emb_gather(const int* __restrict__ ids,
                const float* __restrict__ e0, const float* __restrict__ e1,
                const float* __restrict__ e2, const float* __restrict__ e3,
                unsigned short* __restrict__ embA) {
    const int chunk = blockIdx.x * 256 + threadIdx.x;
    if (chunk >= 2048 * 176) return;
    const int t = chunk / 176;
    const int e8 = (chunk - t * 176) * 8;
    const int i = t >> 2, b = t & 3;
    const int id = ids[b * QLEN + i];
    const float* src = nullptr;
    if (e8 < 1024) {
        if (id < 20000) src = e0 + (size_t)id * 1024 + e8;
    } else if (e8 < 1280) {
        if (id >= 20000 && id < 40000) src = e1 + (size_t)(id - 20000) * 256 + (e8 - 1024);
    } else if (e8 < 1344) {
        if (id >= 40000 && id < 200000) src = e2 + (size_t)(id - 40000) * 64 + (e8 - 1280);
    } else if (e8 < 1360) {
        if (id >= 200000) src = e3 + (size_t)(id - 200000) * 16 + (e8 - 1344);
    }
    uint4 o = {0u, 0u, 0u, 0u};
    if (src) {
        float4 v0 = *(const float4*)src;
        float4 v1 = *(const float4*)(src + 4);
        o.x = (unsigned)f2bf(v0.x * 32.f) | ((unsigned)f2bf(v0.y * 32.f) << 16);
        o.y = (unsigned)f2bf(v0.z * 32.f) | ((unsigned)f2bf(v0.w * 32.f) << 16);
        o.z = (unsigned)f2bf(v1.x * 32.f) | ((unsigned)f2bf(v1.y * 32.f) << 16);
        o.w = (unsigned)f2bf(v1.z * 32.f) | ((unsigned)f2bf(v1.w * 32.f) << 16);
    }
    *(uint4*)(embA + (size_t)t * EK + e8) = o;
}

// ---------------------------------------------------------------------------
// GEMM: C[M,N] = A[M,K] @ B[K,N], A bf16 row-major, BT = B^T bf16 (N x K)
// 128xBN tile (BN = 128 or 64), 2-phase dbuf global_load_lds, T2 swizzle.
// ---------------------------------------------------------------------------
template <int MODE, int BN>
__global__ __launch_bounds__(256)
void gemm_bt(const unsigned short* __restrict__ A, const unsigned short* __restrict__ BT,
             float* __restrict__ C, unsigned short* __restrict__ Cbf,
             const float* __restrict__ bias,
             const float* __restrict__ rwb, const float* __restrict__ rrb,
             unsigned short* __restrict__ Qw, unsigned short* __restrict__ Qr,
             unsigned short* __restrict__ Kb, unsigned short* __restrict__ VTb,
             int M, int N, int K) {
    constexpr int NF = BN / 32;           // n-frags per wave
    __shared__ unsigned short lA[2][128 * 64];
    __shared__ unsigned short lB[2][BN * 64];
    const int tid = threadIdx.x;
    const int w = tid >> 6, l = tid & 63;
    const int lane15 = l & 15, lh = l >> 4;
    const int bm = blockIdx.y, bn = blockIdx.x;
    const int wr = (w >> 1) * 64, wc = (w & 1) * (BN / 2);

    f32x4 acc[4][NF] = {};

    const unsigned short* gA = A + (size_t)(bm * 128) * K;
    const unsigned short* gB = BT + (size_t)(bn * BN) * K;

    auto stage = [&](int buf, int k0) {
#pragma unroll
        for (int s = 0; s < 4; ++s) {
            int g = tid + s * 256, row = g >> 3;
            gload16(gA + (size_t)row * K + k0 + ((g & 7) ^ (row & 7)) * 8,
                    lA[buf] + g * 8);
        }
#pragma unroll
        for (int s = 0; s < BN / 32; ++s) {
            int g = tid + s * 256, row = g >> 3;
            gload16(gB + (size_t)row * K + k0 + ((g & 7) ^ (row & 7)) * 8,
                    lB[buf] + g * 8);
        }
    };

    stage(0, 0);
    __syncthreads();
    int cur = 0;
    for (int k0 = 0; k0 < K; k0 += 64) {
        if (k0 + 64 < K) stage(cur ^ 1, k0 + 64);   // overlap with compute below
        const unsigned short* cA = lA[cur];
        const unsigned short* cB = lB[cur];
#pragma unroll
        for (int kk = 0; kk < 2; ++kk) {
            bf16x8 af[4], bfr[NF];
#pragma unroll
            for (int f = 0; f < 4; ++f)
                af[f] = lds_read8_sw(cA, wr + f * 16 + lane15, kk * 64 + lh * 16);
#pragma unroll
            for (int f = 0; f < NF; ++f)
                bfr[f] = lds_read8_sw(cB, wc + f * 16 + lane15, kk * 64 + lh * 16);
#pragma unroll
            for (int mi = 0; mi < 4; ++mi)
#pragma unroll
                for (int ni = 0; ni < NF; ++ni)
                    acc[mi][ni] = __builtin_amdgcn_mfma_f32_16x16x32_bf16(
                        af[mi], bfr[ni], acc[mi][ni], 0, 0, 0);
        }
        __syncthreads();   // drains prefetch loads; orders buffer reuse
        cur ^= 1;
    }

#pragma unroll
    for (int mi = 0; mi < 4; ++mi) {
        int rowb = bm * 128 + wr + mi * 16 + lh * 4;   // multiple of 4
#pragma unroll
        for (int ni = 0; ni < NF; ++ni) {
            int col = bn * BN + wc + ni * 16 + lane15;
#pragma unroll
            for (int r = 0; r < 4; ++r) {
                float x = acc[mi][ni][r];
                if (MODE == 0) {
                    C[(size_t)(rowb + r) * N + col] = x;
                } else if (MODE == 1) {
                    x += bias[col];
                    Cbf[(size_t)(rowb + r) * N + col] = f2bf(x > 0.f ? x : 0.f);
                } else if (MODE == 2) {
                    C[(size_t)(rowb + r) * N + col] = x + bias[col];
                } else if (MODE == 3) {
                    int j = rowb >> 2;
                    int bb_ = r;
                    if (col < 1024) {
                        if (j >= MLEN) {
                            int i = j - MLEN, n = col >> 6, d = col & 63;
                            size_t o = ((size_t)(bb_ * NH + n) * QLEN + i) * DH + d;
                            Qw[o] = f2bf(x + rwb[col]);
                            Qr[o] = f2bf(x + rrb[col]);
                        }
                    } else if (col < 2048) {
                        int c2 = col - 1024, n = c2 >> 6, d = c2 & 63;
                        Kb[((size_t)(bb_ * NH + n) * KLEN + j) * DH + d] = f2bf(x);
                    } else {
                        int c2 = col - 2048, n = c2 >> 6, d = c2 & 63;
                        VTb[((size_t)(bb_ * NH + n) * DH + d) * KLEN + j] = f2bf(x);
                    }
                } else { // MODE 4
                    int j = rowb + r;
                    int n = col >> 6, d = col & 63;
                    Kb[((size_t)n * KLEN + j) * DH + d] = f2bf(x);  // Kb := Rb here
                }
            }
        }
    }
}

// ---------------------------------------------------------------------------
// Positional embedding table (1024 x 1024), bf16
// ---------------------------------------------------------------------------
__global__ __launch_bounds__(256)
void pos_kernel(unsigned short* __restrict__ posbf) {
    const int p = blockIdx.x, tid = threadIdx.x;
    const float ps = (float)(KLEN - 1 - p);
    const float c = -2.0f * 9.210340371976184f / 1024.0f; // -2*ln(10000)/D
#pragma unroll
    for (int j4 = 0; j4 < 4; ++j4) {
        int j = tid + j4 * 256;
        int m = (j < 512) ? j : j - 512;
        float freq = __expf((float)m * c);
        float ang = ps * freq;
        float v = (j < 512) ? sinf(ang) : cosf(ang);
        posbf[(size_t)p * DM + j] = f2bf(v);
    }
}

// ---------------------------------------------------------------------------
// cat = [mems_l ; h] -> bf16 (4096 x 1024)
// ---------------------------------------------------------------------------
__global__ __launch_bounds__(256)
void cat_kernel(const float* __restrict__ mem_l, const float* __restrict__ h,
                unsigned short* __restrict__ catbf) {
    const int t = blockIdx.x, tid = threadIdx.x;
    const float* src = (t < 2048) ? (mem_l + (size_t)t * DM) : (h + (size_t)(t - 2048) * DM);
    float4 v = ((const float4*)src)[tid];
    uint2 o;
    o.x = (unsigned)f2bf(v.x) | ((unsigned)f2bf(v.y) << 16);
    o.y = (unsigned)f2bf(v.z) | ((unsigned)f2bf(v.w) << 16);
    ((uint2*)(catbf + (size_t)t * DM))[tid] = o;
}

// ---------------------------------------------------------------------------
// Fused rel-attention. Block = (b, n, 64-row i-tile), 8 waves:
// waves 0-3 do even j-tiles, waves 4-7 odd j-tiles (split-j online softmax,
// LDS merge at end). No barriers in loop; K/V/R direct from global (L2).
// ---------------------------------------------------------------------------
__global__ __launch_bounds__(512)
void attn_kernel(const unsigned short* __restrict__ Qw, const unsigned short* __restrict__ Qr,
                 const unsigned short* __restrict__ Kb, const unsigned short* __restrict__ VTb,
                 const unsigned short* __restrict__ Rb, unsigned short* __restrict__ avec) {
    __shared__ float lBD[8][16 * 83];           // per-wave BD band; reused for merge
    __shared__ unsigned short lP[8][16 * 64];   // per-wave P roundtrip (swizzled)

    const int tid = threadIdx.x;
    const int w = tid >> 6, l = tid & 63;
    const int wp = w & 3, jg = w >> 2;          // row-group, j-parity group
    const int lane15 = l & 15, lh = l >> 4;
    const int blk = blockIdx.x;
    const int bn = blk & 63;          // blk%8 == bn%8 -> all it of one head on one XCD
    const int it = blk >> 6;
    const int n = bn & 15, b = bn >> 4;
    const int i0 = it * 64;
    const int rowl = wp * 16 + lh * 4;

    // Q fragments (resident)
    bf16x8 qw[2], qr[2];
    {
        size_t qb = ((size_t)bn * QLEN + i0 + wp * 16 + lane15) * DH + lh * 8;
        qw[0] = *(const bf16x8*)(Qw + qb);
        qw[1] = *(const bf16x8*)(Qw + qb + 32);
        qr[0] = *(const bf16x8*)(Qr + qb);
        qr[1] = *(const bf16x8*)(Qr + qb + 32);
    }

    const unsigned short* Kh = Kb + (size_t)bn * KLEN * DH;
    const unsigned short* Vh = VTb + (size_t)bn * DH * KLEN;
    const unsigned short* Rh = Rb + (size_t)n * KLEN * DH;

    f32x4 oacc[4] = {};
    float mrow[4], srow[4];
#pragma unroll
    for (int r = 0; r < 4; ++r) { mrow[r] = -1e30f; srow[r] = 0.f; }

    const int ntiles = it + 9;
    for (int jt = jg; jt < ntiles; jt += 2) {
        const int j0 = jt * 64;
        // ---- load K (8) and R (10) fragments directly from global ----
        bf16x8 kf[2][4], rf[2][5];
#pragma unroll
        for (int f = 0; f < 4; ++f) {
            const unsigned short* p = Kh + (size_t)(j0 + f * 16 + lane15) * DH + lh * 8;
            kf[0][f] = *(const bf16x8*)p;
            kf[1][f] = *(const bf16x8*)(p + 32);
        }
#pragma unroll
        for (int f = 0; f < 5; ++f) {
            int rr = 496 + 64 * (jt - it) - 16 * wp + 16 * f + lane15;
            if (rr > 1023) rr = 1023;   // clamped rows are always masked
            const unsigned short* p = Rh + (size_t)rr * DH + lh * 8;
            rf[0][f] = *(const bf16x8*)p;
            rf[1][f] = *(const bf16x8*)(p + 32);
        }

        f32x4 sac[4] = {};
        f32x4 bd[5] = {};
        __builtin_amdgcn_s_setprio(1);
#pragma unroll
        for (int kk = 0; kk < 2; ++kk) {
#pragma unroll
            for (int f = 0; f < 4; ++f)
                sac[f] = __builtin_amdgcn_mfma_f32_16x16x32_bf16(qw[kk], kf[kk][f], sac[f], 0, 0, 0);
#pragma unroll
            for (int f = 0; f < 5; ++f)
                bd[f] = __builtin_amdgcn_mfma_f32_16x16x32_bf16(qr[kk], rf[kk][f], bd[f], 0, 0, 0);
        }
        __builtin_amdgcn_s_setprio(0);

        // park BD (f32) for the diagonal-band gather (per-wave region)
#pragma unroll
        for (int f = 0; f < 5; ++f)
#pragma unroll
            for (int r = 0; r < 4; ++r)
                lBD[w][(lh * 4 + r) * 83 + lane15 + 16 * f] = bd[f][r];

        float pv[4][4];
        float tmax[4] = {-1e30f, -1e30f, -1e30f, -1e30f};
        const bool lastTile = (jt == it + 8);
#pragma unroll
        for (int f = 0; f < 4; ++f) {
            int lj = lane15 + 16 * f;
#pragma unroll
            for (int r = 0; r < 4; ++r) {
                int cc = 15 + lj - lh * 4 - r;
                float s = (sac[f][r] + lBD[w][(lh * 4 + r) * 83 + cc]) * 0.125f;
                if (lastTile && (lj > rowl + r)) s = -1e30f;
                pv[f][r] = s;
                tmax[r] = fmaxf(tmax[r], s);
            }
        }
#pragma unroll
        for (int off = 1; off < 16; off <<= 1)
#pragma unroll
            for (int r = 0; r < 4; ++r)
                tmax[r] = fmaxf(tmax[r], __shfl_xor(tmax[r], off));

        // T13 defer-max: skip rescale while per-tile max growth <= 8
        bool grow = false;
#pragma unroll
        for (int r = 0; r < 4; ++r) grow = grow || (tmax[r] > mrow[r] + 8.f);
        if (__any(grow)) {
#pragma unroll
            for (int r = 0; r < 4; ++r) {
                float nm = fmaxf(mrow[r], tmax[r]);
                float sc = __expf(mrow[r] - nm);
                mrow[r] = nm;
                srow[r] *= sc;
#pragma unroll
                for (int f = 0; f < 4; ++f) oacc[f][r] *= sc;
            }
        }
        float tsum[4];
#pragma unroll
        for (int r = 0; r < 4; ++r) {
            float ts = 0.f;
#pragma unroll
            for (int f = 0; f < 4; ++f) {
                float e = __expf(pv[f][r] - mrow[r]);
                pv[f][r] = e;
                ts += e;
            }
            tsum[r] = ts;
        }
#pragma unroll
        for (int off = 1; off < 16; off <<= 1)
#pragma unroll
            for (int r = 0; r < 4; ++r)
                tsum[r] += __shfl_xor(tsum[r], off);
#pragma unroll
        for (int r = 0; r < 4; ++r) srow[r] += tsum[r];

        // P -> bf16 LDS (swizzled, per-wave), reload as A-fragments
#pragma unroll
        for (int f = 0; f < 4; ++f)
#pragma unroll
            for (int r = 0; r < 4; ++r) {
                int row = lh * 4 + r, cb2 = (lane15 + 16 * f) * 2;
                *(unsigned short*)((char*)lP[w] + row * 128 + (cb2 ^ ((row & 7) << 4))) =
                    f2bf(pv[f][r]);
            }
        bf16x8 pa[2];
        pa[0] = lds_read8_sw(lP[w], lane15, lh * 16);
        pa[1] = lds_read8_sw(lP[w], lane15, 64 + lh * 16);

        __builtin_amdgcn_s_setprio(1);
#pragma unroll
        for (int kk = 0; kk < 2; ++kk) {
#pragma unroll
            for (int f = 0; f < 4; ++f) {
                bf16x8 vb = *(const bf16x8*)(Vh + (size_t)(f * 16 + lane15) * KLEN + j0 + kk * 32 + lh * 8);
                oacc[f] = __builtin_amdgcn_mfma_f32_16x16x32_bf16(pa[kk], vb, oacc[f], 0, 0, 0);
            }
        }
        __builtin_amdgcn_s_setprio(0);
    }

    // ---- merge the two j-parity groups (pair: wave wp <- wave wp+4) ----
    __syncthreads();
    float* og = (float*)&lBD[wp][0];        // O2 (16x64, stride 65)
    float* mg = (float*)&lBD[4 + wp][0];    // m2[16], s2[16]
    if (jg == 1) {
#pragma unroll
        for (int f = 0; f < 4; ++f)
#pragma unroll
            for (int r = 0; r < 4; ++r)
                og[(lh * 4 + r) * 65 + lane15 + 16 * f] = oacc[f][r];
        if (lane15 == 0) {
#pragma unroll
            for (int r = 0; r < 4; ++r) {
                mg[lh * 4 + r] = mrow[r];
                mg[16 + lh * 4 + r] = srow[r];
            }
        }
    }
    __syncthreads();
    if (jg == 0) {
#pragma unroll
        for (int r = 0; r < 4; ++r) {
            float m2 = mg[lh * 4 + r], s2 = mg[16 + lh * 4 + r];
            float m = fmaxf(mrow[r], m2);
            float a1 = __expf(mrow[r] - m), a2 = __expf(m2 - m);
            float inv = 1.0f / (srow[r] * a1 + s2 * a2);
            int i = i0 + rowl + r;
            int t = i * 4 + b;
#pragma unroll
            for (int f = 0; f < 4; ++f) {
                float o2 = og[(lh * 4 + r) * 65 + lane15 + 16 * f];
                int col = n * 64 + lane15 + 16 * f;
                avec[(size_t)t * DM + col] = f2bf((oacc[f][r] * a1 + o2 * a2) * inv);
            }
        }
    }
}

// ---------------------------------------------------------------------------
// LayerNorm: h = LN(hin + res) * g + b ; emits f32 h and bf16 h
// ---------------------------------------------------------------------------
__global__ __launch_bounds__(256)
void ln_kernel(const float* __restrict__ hin, const float* __restrict__ res,
               const float* __restrict__ g, const float* __restrict__ bb,
               float* __restrict__ hout, unsigned short* __restrict__ hbf) {
    __shared__ float ls[8];
    const int t = blockIdx.x, tid = threadIdx.x;
    float4 x = ((const float4*)(hin + (size_t)t * DM))[tid];
    float4 rr = ((const float4*)(res + (size_t)t * DM))[tid];
    float v0 = x.x + rr.x, v1 = x.y + rr.y, v2 = x.z + rr.z, v3 = x.w + rr.w;
    float s = v0 + v1 + v2 + v3;
    float sq = v0 * v0 + v1 * v1 + v2 * v2 + v3 * v3;
#pragma unroll
    for (int off = 1; off < 64; off <<= 1) {
        s += __shfl_xor(s, off);
        sq += __shfl_xor(sq, off);
    }
    const int w = tid >> 6;
    if ((tid & 63) == 0) { ls[w] = s; ls[4 + w] = sq; }
    __syncthreads();
    s = ls[0] + ls[1] + ls[2] + ls[3];
    sq = ls[4] + ls[5] + ls[6] + ls[7];
    float mu = s * (1.f / 1024.f);
    float var = sq * (1.f / 1024.f) - mu * mu;
    float rstd = rsqrtf(var + 1e-5f);
    float y[4] = {v0, v1, v2, v3};
    float4 of;
    uint2 ob;
    float* op = &of.x;
#pragma unroll
    for (int j = 0; j < 4; ++j) {
        int d = tid * 4 + j;
        op[j] = (y[j] - mu) * rstd * g[d] + bb[d];
    }
    ob.x = (unsigned)f2bf(of.x) | ((unsigned)f2bf(of.y) << 16);
    ob.y = (unsigned)f2bf(of.z) | ((unsigned)f2bf(of.w) << 16);
    ((float4*)(hout + (size_t)t * DM))[tid] = of;
    ((uint2*)(hbf + (size_t)t * DM))[tid] = ob;
}

__global__ __launch_bounds__(256)
void out_kernel(const float* __restrict__ h, float* __restrict__ out) {
    const int t = blockIdx.x, tid = threadIdx.x;
    const int i = t >> 2, b = t & 3;
    ((float4*)(out + ((size_t)b * QLEN + i) * DM))[tid] =
        ((const float4*)(h + (size_t)t * DM))[tid];
}

// ---------------------------------------------------------------------------
extern "C" void kernel_launch(void* const* d_in, const int* in_sizes, int n_in,
                              void* d_out, int out_size, void* d_ws, size_t ws_size,
                              hipStream_t stream) {
    const int* ids = (const int*)d_in[0];
    const float* mems = (const float*)d_in[1];
    const float* embp[4] = {nullptr, nullptr, nullptr, nullptr};
    const float* projp[4] = {nullptr, nullptr, nullptr, nullptr};
    const long long esz[4] = {20000LL * 1024, 20000LL * 256, 160000LL * 64, 67735LL * 16};
    const long long psz[4] = {1024LL * 1024, 256LL * 1024, 64LL * 1024, 16LL * 1024};
    for (int idx = 2; idx <= 9 && idx < n_in; ++idx) {
        long long s = in_sizes[idx];
        for (int c = 0; c < 4; ++c) {
            if (s == esz[c]) embp[c] = (const float*)d_in[idx];
            else if (s == psz[c]) projp[c] = (const float*)d_in[idx];
        }
    }
    const float* qkvW = (const float*)d_in[10];
    const float* rW   = (const float*)d_in[11];
    const float* oW   = (const float*)d_in[12];
    const float* rwb  = (const float*)d_in[13];
    const float* rrb  = (const float*)d_in[14];
    const float* ln1g = (const float*)d_in[15];
    const float* ln1b = (const float*)d_in[16];
    const float* ffw1 = (const float*)d_in[17];
    const float* ffb1 = (const float*)d_in[18];
    const float* ffw2 = (const float*)d_in[19];
    const float* ffb2 = (const float*)d_in[20];
    const float* ln2g = (const float*)d_in[21];
    const float* ln2b = (const float*)d_in[22];

    size_t off = 0;
    char* base = (char*)d_ws;
    auto alloc = [&](size_t bytes) -> char* {
        char* p = base + off;
        off = (off + bytes + 255) & ~(size_t)255;
        return p;
    };
    unsigned short* qkvT  = (unsigned short*)alloc(3072ull * 1024 * 2);
    unsigned short* rT    = (unsigned short*)alloc(1024ull * 1024 * 2);
    unsigned short* oT    = (unsigned short*)alloc(1024ull * 1024 * 2);
    unsigned short* w1T   = (unsigned short*)alloc(4096ull * 1024 * 2);
    unsigned short* w2T   = (unsigned short*)alloc(1024ull * 4096 * 2);
    unsigned short* embA  = (unsigned short*)alloc(2048ull * EK * 2);
    unsigned short* embBT = (unsigned short*)alloc(1024ull * EK * 2);
    float* h              = (float*)alloc(2048ull * 1024 * 4);
    unsigned short* hbf   = (unsigned short*)alloc(2048ull * 1024 * 2);
    unsigned short* catb  = (unsigned short*)alloc(4096ull * 1024 * 2);
    unsigned short* posb  = (unsigned short*)alloc(1024ull * 1024 * 2);
    unsigned short* Qw    = (unsigned short*)alloc(4ull * 16 * 512 * 64 * 2);
    unsigned short* Qr    = (unsigned short*)alloc(4ull * 16 * 512 * 64 * 2);
    unsigned short* Kb    = (unsigned short*)alloc(4ull * 16 * 1024 * 64 * 2);
    unsigned short* VTb   = (unsigned short*)alloc(4ull * 16 * 1024 * 64 * 2);
    unsigned short* Rb    = (unsigned short*)alloc(16ull * 1024 * 64 * 2);
    unsigned short* avec  = (unsigned short*)alloc(2048ull * 1024 * 2);
    float* resid          = (float*)alloc(2048ull * 1024 * 4);
    unsigned short* ff1b  = (unsigned short*)alloc(2048ull * 4096 * 2);
    (void)ws_size; (void)out_size;

    // ---- embeddings (gather + GEMM) + positional table ----
    emb_gather<<<(2048 * 176 + 255) / 256, 256, 0, stream>>>(
        ids, embp[0], embp[1], embp[2], embp[3], embA);
    transpose_pad<<<dim3(32, 32), 256, 0, stream>>>(projp[0], embBT, 1024, 1024, EK, 0);
    transpose_pad<<<dim3(32, 8),  256, 0, stream>>>(projp[1], embBT, 256,  1024, EK, 1024);
    transpose_pad<<<dim3(32, 2),  256, 0, stream>>>(projp[2], embBT, 64,   1024, EK, 1280);
    transpose_pad<<<dim3(32, 2),  256, 0, stream>>>(projp[3], embBT, 16,   1024, EK, 1344);
    pos_kernel<<<1024, 256, 0, stream>>>(posb);
    gemm_bt<0, 128><<<dim3(1024 / 128, 2048 / 128), 256, 0, stream>>>(
        embA, embBT, h, nullptr, nullptr, nullptr, nullptr, nullptr, nullptr, nullptr, nullptr,
        2048, 1024, EK);

    for (int l = 0; l < N_LAYER; ++l) {
        const float* qkvWl = qkvW + (size_t)l * 1024 * 3072;
        const float* rWl   = rW + (size_t)l * 1024 * 1024;
        const float* oWl   = oW + (size_t)l * 1024 * 1024;
        const float* w1l   = ffw1 + (size_t)l * 1024 * 4096;
        const float* w2l   = ffw2 + (size_t)l * 4096 * 1024;

        transpose_all<<<13312, 256, 0, stream>>>(qkvWl, rWl, oWl, w1l, w2l,
                                                 qkvT, rT, oT, w1T, w2T);

        cat_kernel<<<4096, 256, 0, stream>>>(mems + (size_t)l * 2048 * 1024, h, catb);

        gemm_bt<3, 128><<<dim3(3072 / 128, 4096 / 128), 256, 0, stream>>>(
            catb, qkvT, nullptr, nullptr, nullptr,
            rwb + l * 1024, rrb + l * 1024, Qw, Qr, Kb, VTb, 4096, 3072, 1024);

        gemm_bt<4, 64><<<dim3(1024 / 64, 1024 / 128), 256, 0, stream>>>(
            posb, rT, nullptr, nullptr, nullptr,
            nullptr, nullptr, nullptr, nullptr, Rb, nullptr, 1024, 1024, 1024);

        attn_kernel<<<512, 512, 0, stream>>>(Qw, Qr, Kb, VTb, Rb, avec);

        gemm_bt<0, 64><<<dim3(1024 / 64, 2048 / 128), 256, 0, stream>>>(
            avec, oT, resid, nullptr, nullptr, nullptr, nullptr, nullptr, nullptr, nullptr, nullptr,
            2048, 1024, 1024);
        ln_kernel<<<2048, 256, 0, stream>>>(h, resid, ln1g + l * 1024, ln1b + l * 1024, h, hbf);

        gemm_bt<1, 128><<<dim3(4096 / 128, 2048 / 128), 256, 0, stream>>>(
            hbf, w1T, nullptr, ff1b, ffb1 + l * 4096, nullptr, nullptr, nullptr, nullptr, nullptr, nullptr,
            2048, 4096, 1024);
        gemm_bt<2, 64><<<dim3(1024 / 64, 2048 / 128), 256, 0, stream>>>(
            ff1b, w2T, resid, nullptr, ffb2 + l * 1024, nullptr, nullptr, nullptr, nullptr, nullptr, nullptr,
            2048, 1024, 4096);
        ln_kernel<<<2048, 256, 0, stream>>>(h, resid, ln2g + l * 1024, ln2b + l * 1024, h, hbf);
    }

    out_kernel<<<2048, 256, 0, stream>>>(h, (float*)d_out);
}